// Round 23
// baseline (331.343 us; speedup 1.0000x reference)
//
#include <hip/hip_runtime.h>
#include <hip/hip_bf16.h>

#define BATCH 2
#define NTOK  32768
#define CH    256
#define NH    8
#define HDIM  32
#define NG    32
#define NSC   64
#define NDC   32

typedef __attribute__((ext_vector_type(8))) short short8v;
typedef __attribute__((ext_vector_type(4))) short short4v;
typedef __attribute__((ext_vector_type(4))) float f32x4;

static __device__ __forceinline__ short f2bf(float f) {
    __hip_bfloat16 h = __float2bfloat16(f);
    return __builtin_bit_cast(short, h);
}
static __device__ __forceinline__ float bf2f(short s) {
    return __bfloat162float(__builtin_bit_cast(__hip_bfloat16, s));
}

// ---------------------------------------------------------------------------
// Prep kernel: 4 weight transposes (blocks 0-639) + kcomb (blocks 640-895).
// ---------------------------------------------------------------------------
static __device__ __forceinline__ void transpose_tile(
    const float* __restrict__ in, __hip_bfloat16* __restrict__ out,
    int K, int N, int blk, int tid)
{
    __shared__ float t[32][33];
    const int nb = N >> 5;
    const int bk = blk / nb;
    const int bn = blk % nb;
    const int c = tid & 31, r0 = tid >> 5;
    #pragma unroll
    for (int i = 0; i < 4; ++i) {
        const int r = r0 + i * 8;
        t[r][c] = in[(long)(bk * 32 + r) * N + bn * 32 + c];
    }
    __syncthreads();
    #pragma unroll
    for (int i = 0; i < 4; ++i) {
        const int r = r0 + i * 8;
        out[(long)(bn * 32 + r) * K + bk * 32 + c] = __float2bfloat16(t[c][r]);
    }
}

__global__ __launch_bounds__(256) void kprep(
    const float* __restrict__ Wfx, __hip_bfloat16* __restrict__ wcat,
    const float* __restrict__ Wout, __hip_bfloat16* __restrict__ woutt,
    const float* __restrict__ Wm1, __hip_bfloat16* __restrict__ w1t,
    const float* __restrict__ Wm2, __hip_bfloat16* __restrict__ w2t,
    const float* __restrict__ Wx, const float* __restrict__ bx,
    const float* __restrict__ Wsl, const float* __restrict__ bsl,
    float* __restrict__ bcomb)
{
    const int b = blockIdx.x, tid = threadIdx.x;
    if (b < 64)       { transpose_tile(Wfx,  wcat,  256, 256,  b,       tid); return; }
    else if (b < 128) { transpose_tile(Wout, woutt, 256, 256,  b - 64,  tid); return; }
    else if (b < 384) { transpose_tile(Wm1,  w1t,   256, 1024, b - 128, tid); return; }
    else if (b < 640) { transpose_tile(Wm2,  w2t,   1024, 256, b - 384, tid); return; }
    __shared__ float wcol[32];
    const int hc = b - 640;
    const int h = hc >> 5, g = hc & 31;
    if (tid < 32) wcol[tid] = Wsl[tid * 32 + g];
    __syncthreads();
    float a = 0.f;
    #pragma unroll
    for (int d = 0; d < 32; ++d) a += Wx[tid * 256 + h * 32 + d] * wcol[d];
    (wcat + 65536)[(long)hc * 256 + tid] = __float2bfloat16(a);
    if (tid == 0) {
        float s = bsl[g];
        #pragma unroll
        for (int d = 0; d < 32; ++d) s += bx[h * 32 + d] * wcol[d];
        bcomb[hc] = s;
    }
}

// ---------------------------------------------------------------------------
// Kernel 1 (MFMA, 8 waves / 512 thr): LN1 + GEMM + slice softmax.
// v2: TWO N-passes of 256 cols each (wave grid 2m x 4n, acc[2][4] = 32 acc
// regs) -> fits the 64-arch-VGPR clamp without spill. A stays in LDS [0,32K);
// each pass's 64x256 bf16 output uses [32K,64K), drained before reuse.
// ---------------------------------------------------------------------------
__global__ __launch_bounds__(512, 4) void k1_mfma(
    const float* __restrict__ fx,
    const float* __restrict__ g1, const float* __restrict__ b1,
    const __hip_bfloat16* __restrict__ wcat,   // [512][256]
    const float* __restrict__ bfx, const float* __restrict__ bcomb,
    const float* __restrict__ temp,
    __hip_bfloat16* __restrict__ fxm_o, __hip_bfloat16* __restrict__ sw_o)
{
    __shared__ __align__(16) char lds[65536];
    const int tid = threadIdx.x;
    const int lane = tid & 63, wid = tid >> 6;   // 8 waves
    const long tok0 = (long)blockIdx.x * 64;
    const int col = lane & 15, kq = lane >> 4;
    const int swz = (col & 7) << 4;
    const int ep = ((kq * 16) ^ swz) & 48;
    const int e0 = (swz & 64) | ep;
    const int e1 = ((swz & 64) ^ 64) | ep;
    const int ab0 = col * 512 + e0, ab1 = col * 512 + e1;

    // ---- LN1 -> A (bf16, swizzled, [0,32K)). Each wave: 8 tokens. ----
    {
        const float4 gv = *reinterpret_cast<const float4*>(g1 + lane * 4);
        const float4 bv = *reinterpret_cast<const float4*>(b1 + lane * 4);
        #pragma unroll
        for (int tt = 0; tt < 8; ++tt) {
            const int r = wid * 8 + tt;
            const float4 v = *reinterpret_cast<const float4*>(fx + (tok0 + r) * 256 + lane * 4);
            float s = v.x + v.y + v.z + v.w;
            float s2 = v.x * v.x + v.y * v.y + v.z * v.z + v.w * v.w;
            #pragma unroll
            for (int off = 32; off; off >>= 1) {
                s  += __shfl_xor(s,  off);
                s2 += __shfl_xor(s2, off);
            }
            const float mean = s * (1.f / 256.f);
            const float rs = rsqrtf(s2 * (1.f / 256.f) - mean * mean + 1e-5f);
            short4v o;
            o[0] = f2bf((v.x - mean) * rs * gv.x + bv.x);
            o[1] = f2bf((v.y - mean) * rs * gv.y + bv.y);
            o[2] = f2bf((v.z - mean) * rs * gv.z + bv.z);
            o[3] = f2bf((v.w - mean) * rs * gv.w + bv.w);
            const int addr = r * 512 + ((lane * 8) ^ ((r & 7) << 4));
            *reinterpret_cast<short4v*>(lds + addr) = o;
        }
    }
    __syncthreads();

    const int mh = wid >> 2;     // 0..1: row half
    const int nq = wid & 3;      // 0..3: 64-col slice within pass
    const short* wps = reinterpret_cast<const short*>(wcat) + (nq * 64 + col) * 256 + kq * 8;

    #pragma unroll 1
    for (int p = 0; p < 2; ++p) {
        // ---- GEMM pass p: C(64x256) = A @ wcat[p*256.., :] ----
        f32x4 acc[2][4];
        #pragma unroll
        for (int mt = 0; mt < 2; ++mt)
            #pragma unroll
            for (int nt = 0; nt < 4; ++nt) acc[mt][nt] = (f32x4){0.f, 0.f, 0.f, 0.f};

        #pragma unroll 2
        for (int j = 0; j < 4; ++j) {
            short8v a0[2], a1[2];
            #pragma unroll
            for (int mt = 0; mt < 2; ++mt) {
                a0[mt] = *reinterpret_cast<const short8v*>(lds + mh * 16384 + mt * 8192 + j * 128 + ab0);
                a1[mt] = *reinterpret_cast<const short8v*>(lds + mh * 16384 + mt * 8192 + j * 128 + ab1);
            }
            #pragma unroll
            for (int nt = 0; nt < 4; ++nt) {
                const short8v b0 = *reinterpret_cast<const short8v*>(wps + p * 65536 + nt * 4096 + j * 64);
                const short8v b1 = *reinterpret_cast<const short8v*>(wps + p * 65536 + nt * 4096 + j * 64 + 32);
                #pragma unroll
                for (int mt = 0; mt < 2; ++mt) {
                    acc[mt][nt] = __builtin_amdgcn_mfma_f32_16x16x32_bf16(a0[mt], b0, acc[mt][nt], 0, 0, 0);
                    acc[mt][nt] = __builtin_amdgcn_mfma_f32_16x16x32_bf16(a1[mt], b1, acc[mt][nt], 0, 0, 0);
                }
            }
        }
        __syncthreads();   // upper half free (p0: unused; p1: fxm store drained)

        // ---- write pass output bf16 [64][256] swizzled -> [32K,64K) ----
        const float* bias = p ? bcomb : bfx;
        #pragma unroll
        for (int nt = 0; nt < 4; ++nt) {
            const int cl = nq * 64 + nt * 16 + col;
            const float bb = bias[cl];
            #pragma unroll
            for (int mt = 0; mt < 2; ++mt) {
                #pragma unroll
                for (int r = 0; r < 4; ++r) {
                    const int row = mh * 32 + mt * 16 + kq * 4 + r;
                    const int byte = 32768 + row * 512 + ((cl * 2) ^ ((row & 7) << 4));
                    *reinterpret_cast<short*>(lds + byte) = f2bf(acc[mt][nt][r] + bb);
                }
            }
        }
        __syncthreads();   // pass output ready for all waves

        if (p == 0) {
            // ---- coalesced fxm store from [32K,64K) ----
            #pragma unroll
            for (int it = 0; it < 4; ++it) {
                const int idx = it * 512 + tid;       // 2048 chunks of 16B
                const int row = idx >> 5, ch = idx & 31;
                const short8v val = *reinterpret_cast<const short8v*>(
                    lds + 32768 + row * 512 + ((ch * 16) ^ ((row & 7) << 4)));
                *reinterpret_cast<short8v*>(
                    reinterpret_cast<short*>(fxm_o) + (tok0 + row) * 256 + ch * 8) = val;
            }
            // next iteration's first barrier guarantees these reads complete
            // in all waves before the upper half is overwritten.
        }
    }

    // ---- slice softmax on logits in [32K,64K): one (t,h) per thread ----
    {
        const int t = tid >> 3, h = tid & 7;
        const float it_ = 1.f / temp[h];
        float lg[32];
        #pragma unroll
        for (int g = 0; g < 32; ++g) {
            const int byte = 32768 + t * 512 + (((h * 32 + g) * 2) ^ ((t & 7) << 4));
            lg[g] = bf2f(*reinterpret_cast<const short*>(lds + byte)) * it_;
        }
        float mx = -1e30f;
        #pragma unroll
        for (int g = 0; g < 32; ++g) mx = fmaxf(mx, lg[g]);
        float ssum = 0.f;
        #pragma unroll
        for (int g = 0; g < 32; ++g) { lg[g] = __expf(lg[g] - mx); ssum += lg[g]; }
        const float inv = 1.f / ssum;
        #pragma unroll
        for (int g = 0; g < 32; ++g) {
            const int byte = 32768 + t * 512 + (((h * 32 + g) * 2) ^ ((t & 7) << 4));
            *reinterpret_cast<short*>(lds + byte) = f2bf(lg[g] * inv);
        }
    }
    __syncthreads();

    // ---- coalesced sw store from [32K,64K) ----
    #pragma unroll
    for (int it = 0; it < 4; ++it) {
        const int idx = it * 512 + tid;
        const int row = idx >> 5, ch = idx & 31;
        const short8v val = *reinterpret_cast<const short8v*>(
            lds + 32768 + row * 512 + ((ch * 16) ^ ((row & 7) << 4)));
        *reinterpret_cast<short8v*>(
            reinterpret_cast<short*>(sw_o) + (tok0 + row) * 256 + ch * 8) = val;
    }
}

// ---------------------------------------------------------------------------
// Kernel 2 (8 waves): st partials — wave-local, barrier-free accumulation.
// ---------------------------------------------------------------------------
__global__ __launch_bounds__(512) void k2_st_partial(
    const __hip_bfloat16* __restrict__ fxm, const __hip_bfloat16* __restrict__ sw,
    float* __restrict__ pst, float* __restrict__ pn)
{
    __shared__ float psum[8][32][32];
    __shared__ float pns[8][32];
    const int tid = threadIdx.x, wid = tid >> 6, lane = tid & 63;
    const int blk = blockIdx.x;
    const int bh = blk >> 5, chunk = blk & 31;
    const int b = bh >> 3, h = bh & 7;
    const long rbase = (long)b * NTOK + (long)chunk * 1024 + wid * 128;
    const int gB = lane >> 3, dB = lane & 7;
    const short* sp = reinterpret_cast<const short*>(sw) + rbase * 256 + h * 32 + gB * 4;
    const short* fp = reinterpret_cast<const short*>(fxm) + rbase * 256 + h * 32 + dB * 4;

    float acc[4][4];
    float nacc[4];
    #pragma unroll
    for (int i = 0; i < 4; ++i) {
        nacc[i] = 0.f;
        #pragma unroll
        for (int j = 0; j < 4; ++j) acc[i][j] = 0.f;
    }

    #pragma unroll 4
    for (int r = 0; r < 128; ++r) {
        const short4v s4 = *reinterpret_cast<const short4v*>(sp + r * 256);
        const short4v f4 = *reinterpret_cast<const short4v*>(fp + r * 256);
        float sg[4], fd[4];
        #pragma unroll
        for (int i = 0; i < 4; ++i) { sg[i] = bf2f(s4[i]); fd[i] = bf2f(f4[i]); }
        #pragma unroll
        for (int gg = 0; gg < 4; ++gg) {
            nacc[gg] += sg[gg];
            #pragma unroll
            for (int dd = 0; dd < 4; ++dd) acc[gg][dd] += sg[gg] * fd[dd];
        }
    }

    #pragma unroll
    for (int gg = 0; gg < 4; ++gg) {
        #pragma unroll
        for (int dd = 0; dd < 4; ++dd)
            psum[wid][gB * 4 + gg][dB * 4 + dd] = acc[gg][dd];
        if (dB == 0) pns[wid][gB * 4 + gg] = nacc[gg];
    }
    __syncthreads();

    for (int i = tid; i < 1024; i += 512) {
        const int g = i >> 5, d = i & 31;
        float s = 0.f;
        #pragma unroll
        for (int w = 0; w < 8; ++w) s += psum[w][g][d];
        pst[(long)blk * 1024 + i] = s;
    }
    if (tid < 32) {
        float s = 0.f;
        #pragma unroll
        for (int w = 0; w < 8; ++w) s += pns[w][tid];
        pn[blk * 32 + tid] = s;
    }
}

// ---------------------------------------------------------------------------
// Kernel 3: reduce partials -> st; slice self-attn + cross-attn -> ostT (bf16).
// ---------------------------------------------------------------------------
__global__ __launch_bounds__(256) void k3_slice_attn(
    const float* __restrict__ pst, const float* __restrict__ pn,
    const float* __restrict__ ctx,
    const float* __restrict__ Wq, const float* __restrict__ Wk, const float* __restrict__ Wv,
    const float* __restrict__ Wcq, const float* __restrict__ bcq,
    const float* __restrict__ Wck, const float* __restrict__ bck,
    const float* __restrict__ Wcv, const float* __restrict__ bcv,
    const float* __restrict__ mix, __hip_bfloat16* __restrict__ ostT_o)
{
    __shared__ float st[1024], qm[1024], km[1024], vm[1024], cqm[1024];
    __shared__ float ckm[2048], cvm[2048], attn[2048], stok[1024], nb[32];
    const int tid = threadIdx.x;
    const int bh = blockIdx.x;

    if (tid < 32) {
        float s = 0.f;
        for (int c = 0; c < 32; ++c) s += pn[(bh * 32 + c) * 32 + tid];
        nb[tid] = s;
    }
    __syncthreads();
    for (int i = tid; i < 1024; i += 256) {
        float s = 0.f;
        for (int c = 0; c < 32; ++c) s += pst[(long)(bh * 32 + c) * 1024 + i];
        st[i] = s / (nb[i >> 5] + 1e-5f);
    }
    __syncthreads();

    for (int i = tid; i < 1024; i += 256) {
        const int g = i >> 5, d = i & 31;
        float aq = 0.f, ak = 0.f, av = 0.f, ac = bcq[d];
        #pragma unroll
        for (int e = 0; e < 32; ++e) {
            const float s = st[g * 32 + e];
            aq += s * Wq[e * 32 + d];
            ak += s * Wk[e * 32 + d];
            av += s * Wv[e * 32 + d];
            ac += s * Wcq[e * 32 + d];
        }
        qm[i] = aq; km[i] = ak; vm[i] = av; cqm[i] = ac;
    }
    const float* cbp = ctx + (long)bh * (NSC * NDC);
    for (int i = tid; i < 2048; i += 256) {
        const int s_ = i >> 5, d = i & 31;
        float w1 = bck[d], w2 = bcv[d];
        #pragma unroll
        for (int e = 0; e < 32; ++e) {
            const float cval = cbp[s_ * 32 + e];
            w1 += cval * Wck[e * 32 + d];
            w2 += cval * Wcv[e * 32 + d];
        }
        ckm[i] = w1; cvm[i] = w2;
    }
    __syncthreads();

    const float scale = 0.17677669529663687f;
    for (int i = tid; i < 1024; i += 256) {
        const int g = i >> 5, m = i & 31;
        float a = 0.f;
        #pragma unroll
        for (int d = 0; d < 32; ++d) a += qm[g * 32 + d] * km[m * 32 + d];
        attn[i] = a * scale;
    }
    __syncthreads();
    if (tid < 32) {
        float mx = -1e30f;
        for (int m = 0; m < 32; ++m) mx = fmaxf(mx, attn[tid * 32 + m]);
        float s = 0.f;
        for (int m = 0; m < 32; ++m) { const float e = expf(attn[tid * 32 + m] - mx); attn[tid * 32 + m] = e; s += e; }
        const float inv = 1.f / s;
        for (int m = 0; m < 32; ++m) attn[tid * 32 + m] *= inv;
    }
    __syncthreads();
    for (int i = tid; i < 1024; i += 256) {
        const int g = i >> 5, d = i & 31;
        float a = 0.f;
        #pragma unroll
        for (int m = 0; m < 32; ++m) a += attn[g * 32 + m] * vm[m * 32 + d];
        stok[i] = a;
    }
    __syncthreads();
    for (int i = tid; i < 2048; i += 256) {
        const int g = i >> 6, s_ = i & 63;
        float a = 0.f;
        #pragma unroll
        for (int d = 0; d < 32; ++d) a += cqm[g * 32 + d] * ckm[s_ * 32 + d];
        attn[i] = a * scale;
    }
    __syncthreads();
    if (tid < 32) {
        float mx = -1e30f;
        for (int m = 0; m < 64; ++m) mx = fmaxf(mx, attn[tid * 64 + m]);
        float s = 0.f;
        for (int m = 0; m < 64; ++m) { const float e = expf(attn[tid * 64 + m] - mx); attn[tid * 64 + m] = e; s += e; }
        const float inv = 1.f / s;
        for (int m = 0; m < 64; ++m) attn[tid * 64 + m] *= inv;
    }
    __syncthreads();
    const float mw = 1.f / (1.f + expf(-mix[0]));
    for (int i = tid; i < 1024; i += 256) {
        const int g = i >> 5, d = i & 31;
        float a = 0.f;
        #pragma unroll
        for (int s_ = 0; s_ < 64; ++s_) a += attn[g * 64 + s_] * cvm[s_ * 32 + d];
        const float val = mw * stok[i] + (1.f - mw) * a;
        ostT_o[(long)bh * 1024 + d * 32 + g] = __float2bfloat16(val);
    }
}

// ---------------------------------------------------------------------------
// Kernel 45 (fused, 8 waves, 64KB LDS): de-slice + Wout GEMM + LN2 + MLP.
// r19/r22-proven: bounds(512,4), A2 double-buffered chunk=128, RMW epilogue.
// ---------------------------------------------------------------------------
__global__ __launch_bounds__(512, 4) void k45_fused(
    const __hip_bfloat16* __restrict__ sw, const __hip_bfloat16* __restrict__ ostT,
    const __hip_bfloat16* __restrict__ woutt, const float* __restrict__ bout,
    const float* __restrict__ fx,
    const float* __restrict__ g2, const float* __restrict__ b2,
    const __hip_bfloat16* __restrict__ w1t, const float* __restrict__ bm1,
    const __hip_bfloat16* __restrict__ w2t, const float* __restrict__ bm2,
    float* __restrict__ out)
{
    __shared__ __align__(16) char lds[65536];
    const int tid = threadIdx.x;
    const int lane = tid & 63, wid = tid >> 6;   // 8 waves
    const long tok0 = (long)blockIdx.x * 64;
    const int b = (int)(tok0 >> 15);
    const int col = lane & 15, kq = lane >> 4;
    const int swz = (col & 7) << 4;
    const int ep = ((kq * 16) ^ swz) & 48;
    const int e0 = (swz & 64) | ep;
    const int e1 = ((swz & 64) ^ 64) | ep;
    const int ab0 = col * 512 + e0, ab1 = col * 512 + e1;
    const int cb0 = col * 256 + e0, cb1 = col * 256 + e1;

    // ---- stage sw -> [0,32K) bf16 swizzled ----
    #pragma unroll
    for (int it = 0; it < 4; ++it) {
        const int idx = it * 512 + tid;
        const int row = idx >> 5, ch = idx & 31;
        const short8v val = *reinterpret_cast<const short8v*>(
            reinterpret_cast<const short*>(sw) + (tok0 + row) * 256 + ch * 8);
        *reinterpret_cast<short8v*>(lds + row * 512 + ((ch * 16) ^ ((row & 7) << 4))) = val;
    }
    __syncthreads();

    // ---- de-slice via MFMA: wave handles head h = wid ----
    {
        f32x4 accal[4][2];
        const int abh = col * 512 + (((wid * 64) | (kq * 16)) ^ swz);
        short8v a[4];
        #pragma unroll
        for (int mt = 0; mt < 4; ++mt)
            a[mt] = *reinterpret_cast<const short8v*>(lds + mt * 8192 + abh);
        #pragma unroll
        for (int nt = 0; nt < 2; ++nt) {
            const int d = nt * 16 + col;
            const short8v bfr = *reinterpret_cast<const short8v*>(
                reinterpret_cast<const short*>(ostT) + ((b * 8 + wid) * 32 + d) * 32 + kq * 8);
            #pragma unroll
            for (int mt = 0; mt < 4; ++mt) {
                accal[mt][nt] = (f32x4){0.f, 0.f, 0.f, 0.f};
                accal[mt][nt] = __builtin_amdgcn_mfma_f32_16x16x32_bf16(
                    a[mt], bfr, accal[mt][nt], 0, 0, 0);
            }
        }
        #pragma unroll
        for (int nt = 0; nt < 2; ++nt) {
            const int cc = wid * 32 + nt * 16 + col;
            #pragma unroll
            for (int mt = 0; mt < 4; ++mt) {
                #pragma unroll
                for (int r = 0; r < 4; ++r) {
                    const int row = mt * 16 + kq * 4 + r;
                    const int byte = 32768 + row * 512 + ((cc * 2) ^ ((row & 7) << 4));
                    *reinterpret_cast<short*>(lds + byte) = f2bf(accal[mt][nt][r]);
                }
            }
        }
    }
    __syncthreads();

    // ---- Wout GEMM ----
    f32x4 acc[4][2];
    #pragma unroll
    for (int mt = 0; mt < 4; ++mt)
        #pragma unroll
        for (int nt = 0; nt < 2; ++nt) acc[mt][nt] = (f32x4){0.f, 0.f, 0.f, 0.f};

    {
        const short* wp = reinterpret_cast<const short*>(woutt) + (wid * 32 + col) * 256 + kq * 8;
        #pragma unroll 2
        for (int j = 0; j < 4; ++j) {
            short8v a0[4], a1[4];
            #pragma unroll
            for (int mt = 0; mt < 4; ++mt) {
                a0[mt] = *reinterpret_cast<const short8v*>(lds + 32768 + mt * 8192 + j * 128 + ab0);
                a1[mt] = *reinterpret_cast<const short8v*>(lds + 32768 + mt * 8192 + j * 128 + ab1);
            }
            #pragma unroll
            for (int nt = 0; nt < 2; ++nt) {
                const short8v b0 = *reinterpret_cast<const short8v*>(wp + nt * 4096 + j * 64);
                const short8v b1 = *reinterpret_cast<const short8v*>(wp + nt * 4096 + j * 64 + 32);
                #pragma unroll
                for (int mt = 0; mt < 4; ++mt) {
                    acc[mt][nt] = __builtin_amdgcn_mfma_f32_16x16x32_bf16(a0[mt], b0, acc[mt][nt], 0, 0, 0);
                    acc[mt][nt] = __builtin_amdgcn_mfma_f32_16x16x32_bf16(a1[mt], b1, acc[mt][nt], 0, 0, 0);
                }
            }
        }
    }

    // ---- stage attn output (acc+bout) as f32 [64][256] ----
    __syncthreads();
    float* lf = reinterpret_cast<float*>(lds);
    #pragma unroll
    for (int nt = 0; nt < 2; ++nt) {
        const int c = wid * 32 + nt * 16 + col;
        const float bb = bout[c];
        #pragma unroll
        for (int mt = 0; mt < 4; ++mt) {
            #pragma unroll
            for (int r = 0; r < 4; ++r) {
                const int row = mt * 16 + kq * 4 + r;
                lf[row * 256 + c] = acc[mt][nt][r] + bb;
            }
        }
    }
    __syncthreads();

    // ---- LN2: read attn tile + fx; store out_attn to global NOW ----
    short4v aout[8];
    {
        const float4 gv = *reinterpret_cast<const float4*>(g2 + lane * 4);
        const float4 bv = *reinterpret_cast<const float4*>(b2 + lane * 4);
        #pragma unroll
        for (int tt = 0; tt < 8; ++tt) {
            const int r = wid * 8 + tt;
            const float4 l4 = *reinterpret_cast<const float4*>(lf + r * 256 + lane * 4);
            const float4 f4 = *reinterpret_cast<const float4*>(fx + (tok0 + r) * 256 + lane * 4);
            float4 oa;
            oa.x = l4.x + f4.x; oa.y = l4.y + f4.y;
            oa.z = l4.z + f4.z; oa.w = l4.w + f4.w;
            *reinterpret_cast<float4*>(out + (tok0 + r) * 256 + lane * 4) = oa;
            float s = oa.x + oa.y + oa.z + oa.w;
            float s2 = oa.x * oa.x + oa.y * oa.y + oa.z * oa.z + oa.w * oa.w;
            #pragma unroll
            for (int off = 32; off; off >>= 1) {
                s  += __shfl_xor(s,  off);
                s2 += __shfl_xor(s2, off);
            }
            const float mean = s * (1.f / 256.f);
            const float rs = rsqrtf(s2 * (1.f / 256.f) - mean * mean + 1e-5f);
            aout[tt][0] = f2bf((oa.x - mean) * rs * gv.x + bv.x);
            aout[tt][1] = f2bf((oa.y - mean) * rs * gv.y + bv.y);
            aout[tt][2] = f2bf((oa.z - mean) * rs * gv.z + bv.z);
            aout[tt][3] = f2bf((oa.w - mean) * rs * gv.w + bv.w);
        }
    }
    __syncthreads();
    #pragma unroll
    for (int tt = 0; tt < 8; ++tt) {
        const int r = wid * 8 + tt;
        const int addr = r * 512 + ((lane * 8) ^ ((r & 7) << 4));
        *reinterpret_cast<short4v*>(lds + addr) = aout[tt];
    }
    __syncthreads();

    // ---- MLP: chunk=128, A2 double-buffered (16KB each), 1 barrier/chunk ----
    const int n0 = wid * 32;
    const int h0 = wid * 16;
    const short* w1s = reinterpret_cast<const short*>(w1t) + (h0 + col) * 256 + kq * 8;
    const short* w2s = reinterpret_cast<const short*>(w2t) + (n0 + col) * 1024 + kq * 8;

    f32x4 accO[4][2];
    #pragma unroll
    for (int mt = 0; mt < 4; ++mt)
        #pragma unroll
        for (int nt = 0; nt < 2; ++nt) accO[mt][nt] = (f32x4){0.f, 0.f, 0.f, 0.f};

    for (int ch = 0; ch < 8; ++ch) {
        const int abuf = 32768 + (ch & 1) * 16384;

        f32x4 accP[4];
        #pragma unroll
        for (int mt = 0; mt < 4; ++mt) accP[mt] = (f32x4){0.f, 0.f, 0.f, 0.f};

        #pragma unroll 1
        for (int j = 0; j < 4; ++j) {
            const short8v b0 = *reinterpret_cast<const short8v*>(w1s + ch * 32768 + j * 64);
            const short8v b1 = *reinterpret_cast<const short8v*>(w1s + ch * 32768 + j * 64 + 32);
            #pragma unroll
            for (int mt = 0; mt < 4; ++mt) {
                const short8v a0 = *reinterpret_cast<const short8v*>(lds + mt * 8192 + j * 128 + ab0);
                const short8v a1 = *reinterpret_cast<const short8v*>(lds + mt * 8192 + j * 128 + ab1);
                accP[mt] = __builtin_amdgcn_mfma_f32_16x16x32_bf16(a0, b0, accP[mt], 0, 0, 0);
                accP[mt] = __builtin_amdgcn_mfma_f32_16x16x32_bf16(a1, b1, accP[mt], 0, 0, 0);
            }
        }

        {
            const float b1v = bm1[ch * 128 + h0 + col];
            const int k2i2 = (h0 + col) * 2;
            #pragma unroll
            for (int mt = 0; mt < 4; ++mt) {
                #pragma unroll
                for (int r = 0; r < 4; ++r) {
                    float m = accP[mt][r] + b1v;
                    const float u = __builtin_fmaf(0.044715f * m, m * m, m);
                    const float e = __expf(-1.5957691216057308f * u);
                    m = m * __builtin_amdgcn_rcpf(1.f + e);
                    const int row = mt * 16 + kq * 4 + r;
                    const int byte = abuf + row * 256 + (k2i2 ^ ((row & 7) << 4));
                    *reinterpret_cast<short*>(lds + byte) = f2bf(m);
                }
            }
        }
        __syncthreads();

        #pragma unroll 1
        for (int j = 0; j < 2; ++j) {
            short8v b20[2], b21[2];
            #pragma unroll
            for (int nt = 0; nt < 2; ++nt) {
                b20[nt] = *reinterpret_cast<const short8v*>(w2s + nt * 16384 + ch * 128 + j * 64);
                b21[nt] = *reinterpret_cast<const short8v*>(w2s + nt * 16384 + ch * 128 + j * 64 + 32);
            }
            #pragma unroll
            for (int mt = 0; mt < 4; ++mt) {
                const short8v x0 = *reinterpret_cast<const short8v*>(lds + abuf + mt * 4096 + j * 128 + cb0);
                const short8v x1 = *reinterpret_cast<const short8v*>(lds + abuf + mt * 4096 + j * 128 + cb1);
                #pragma unroll
                for (int nt = 0; nt < 2; ++nt) {
                    accO[mt][nt] = __builtin_amdgcn_mfma_f32_16x16x32_bf16(x0, b20[nt], accO[mt][nt], 0, 0, 0);
                    accO[mt][nt] = __builtin_amdgcn_mfma_f32_16x16x32_bf16(x1, b21[nt], accO[mt][nt], 0, 0, 0);
                }
            }
        }
    }

    // ---- epilogue: accO+bm2 -> lf; out += mlp (RMW) ----
    __syncthreads();
    #pragma unroll
    for (int nt = 0; nt < 2; ++nt) {
        const int c = n0 + nt * 16 + col;
        const float b2v = bm2[c];
        #pragma unroll
        for (int mt = 0; mt < 4; ++mt) {
            #pragma unroll
            for (int r = 0; r < 4; ++r) {
                const int row = mt * 16 + kq * 4 + r;
                lf[row * 256 + c] = accO[mt][nt][r] + b2v;
            }
        }
    }
    __syncthreads();
    #pragma unroll
    for (int tt = 0; tt < 8; ++tt) {
        const int r = wid * 8 + tt;
        const float4 m4 = *reinterpret_cast<const float4*>(lf + r * 256 + lane * 4);
        const long gidx = (tok0 + r) * 256 + lane * 4;
        const float4 oa = *reinterpret_cast<const float4*>(out + gidx);
        float4 o;
        o.x = oa.x + m4.x; o.y = oa.y + m4.y;
        o.z = oa.z + m4.z; o.w = oa.w + m4.w;
        *reinterpret_cast<float4*>(out + gidx) = o;
    }
}

// ---------------------------------------------------------------------------
extern "C" void kernel_launch(void* const* d_in, const int* in_sizes, int n_in,
                              void* d_out, int out_size, void* d_ws, size_t ws_size,
                              hipStream_t stream)
{
    const float* fx   = (const float*)d_in[0];
    const float* ctx  = (const float*)d_in[1];
    const float* g1   = (const float*)d_in[2];
    const float* b1   = (const float*)d_in[3];
    const float* Wfx  = (const float*)d_in[4];
    const float* bfx  = (const float*)d_in[5];
    const float* Wx   = (const float*)d_in[6];
    const float* bx   = (const float*)d_in[7];
    const float* Wsl  = (const float*)d_in[8];
    const float* bsl  = (const float*)d_in[9];
    const float* temp = (const float*)d_in[10];
    const float* Wq   = (const float*)d_in[11];
    const float* Wk   = (const float*)d_in[12];
    const float* Wv   = (const float*)d_in[13];
    const float* Wcq  = (const float*)d_in[14];
    const float* bcq  = (const float*)d_in[15];
    const float* Wck  = (const float*)d_in[16];
    const float* bck  = (const float*)d_in[17];
    const float* Wcv  = (const float*)d_in[18];
    const float* bcv  = (const float*)d_in[19];
    const float* mix  = (const float*)d_in[20];
    const float* Wout = (const float*)d_in[21];
    const float* bout = (const float*)d_in[22];
    const float* g2   = (const float*)d_in[23];
    const float* b2   = (const float*)d_in[24];
    const float* Wm1  = (const float*)d_in[25];
    const float* bm1  = (const float*)d_in[26];
    const float* Wm2  = (const float*)d_in[27];
    const float* bm2  = (const float*)d_in[28];
    float* out = (float*)d_out;

    char* ws = (char*)d_ws;
    __hip_bfloat16* fxm  = (__hip_bfloat16*)ws;                         // 32MB
    __hip_bfloat16* sw   = (__hip_bfloat16*)(ws + (size_t)33554432);    // 32MB
    float* pst = (float*)(ws + (size_t)67108864);                       // 2MB
    float* pn  = (float*)(ws + (size_t)69206016);                       // 64KB
    __hip_bfloat16* ostT  = (__hip_bfloat16*)(ws + (size_t)69271552);   // 32KB
    __hip_bfloat16* wcat  = (__hip_bfloat16*)(ws + (size_t)69304320);   // 256KB [Wfx^T; Wcomb^T]
    __hip_bfloat16* woutt = (__hip_bfloat16*)(ws + (size_t)69566464);   // 128KB
    __hip_bfloat16* w1t   = (__hip_bfloat16*)(ws + (size_t)69697536);   // 512KB
    __hip_bfloat16* w2t   = (__hip_bfloat16*)(ws + (size_t)70221824);   // 512KB
    float* bcomb          = (float*)(ws + (size_t)70746112);            // 1KB

    kprep<<<896, 256, 0, stream>>>(Wfx, wcat, Wout, woutt, Wm1, w1t, Wm2, w2t,
                                   Wx, bx, Wsl, bsl, bcomb);

    k1_mfma<<<1024, 512, 0, stream>>>(fx, g1, b1, wcat, bfx, bcomb, temp,
                                      fxm, sw);
    k2_st_partial<<<512, 512, 0, stream>>>(fxm, sw, pst, pn);
    k3_slice_attn<<<16, 256, 0, stream>>>(pst, pn, ctx, Wq, Wk, Wv,
                                          Wcq, bcq, Wck, bck, Wcv, bcv, mix, ostT);
    k45_fused<<<1024, 512, 0, stream>>>(sw, ostT, woutt, bout, fx,
                                        g2, b2, w1t, bm1, w2t, bm2, out);
}

// Round 24
// 308.451 us; speedup vs baseline: 1.0742x; 1.0742x over previous
//
#include <hip/hip_runtime.h>
#include <hip/hip_bf16.h>

#define BATCH 2
#define NTOK  32768
#define CH    256
#define NH    8
#define HDIM  32
#define NG    32
#define NSC   64
#define NDC   32

typedef __attribute__((ext_vector_type(8))) short short8v;
typedef __attribute__((ext_vector_type(4))) short short4v;
typedef __attribute__((ext_vector_type(4))) float f32x4;

static __device__ __forceinline__ short f2bf(float f) {
    __hip_bfloat16 h = __float2bfloat16(f);
    return __builtin_bit_cast(short, h);
}
static __device__ __forceinline__ float bf2f(short s) {
    return __bfloat162float(__builtin_bit_cast(__hip_bfloat16, s));
}

// ---------------------------------------------------------------------------
// Prep kernel: 4 weight transposes (blocks 0-639) + kcomb (blocks 640-895).
// ---------------------------------------------------------------------------
static __device__ __forceinline__ void transpose_tile(
    const float* __restrict__ in, __hip_bfloat16* __restrict__ out,
    int K, int N, int blk, int tid)
{
    __shared__ float t[32][33];
    const int nb = N >> 5;
    const int bk = blk / nb;
    const int bn = blk % nb;
    const int c = tid & 31, r0 = tid >> 5;
    #pragma unroll
    for (int i = 0; i < 4; ++i) {
        const int r = r0 + i * 8;
        t[r][c] = in[(long)(bk * 32 + r) * N + bn * 32 + c];
    }
    __syncthreads();
    #pragma unroll
    for (int i = 0; i < 4; ++i) {
        const int r = r0 + i * 8;
        out[(long)(bn * 32 + r) * K + bk * 32 + c] = __float2bfloat16(t[c][r]);
    }
}

__global__ __launch_bounds__(256) void kprep(
    const float* __restrict__ Wfx, __hip_bfloat16* __restrict__ wcat,
    const float* __restrict__ Wout, __hip_bfloat16* __restrict__ woutt,
    const float* __restrict__ Wm1, __hip_bfloat16* __restrict__ w1t,
    const float* __restrict__ Wm2, __hip_bfloat16* __restrict__ w2t,
    const float* __restrict__ Wx, const float* __restrict__ bx,
    const float* __restrict__ Wsl, const float* __restrict__ bsl,
    float* __restrict__ bcomb)
{
    const int b = blockIdx.x, tid = threadIdx.x;
    if (b < 64)       { transpose_tile(Wfx,  wcat,  256, 256,  b,       tid); return; }
    else if (b < 128) { transpose_tile(Wout, woutt, 256, 256,  b - 64,  tid); return; }
    else if (b < 384) { transpose_tile(Wm1,  w1t,   256, 1024, b - 128, tid); return; }
    else if (b < 640) { transpose_tile(Wm2,  w2t,   1024, 256, b - 384, tid); return; }
    __shared__ float wcol[32];
    const int hc = b - 640;
    const int h = hc >> 5, g = hc & 31;
    if (tid < 32) wcol[tid] = Wsl[tid * 32 + g];
    __syncthreads();
    float a = 0.f;
    #pragma unroll
    for (int d = 0; d < 32; ++d) a += Wx[tid * 256 + h * 32 + d] * wcol[d];
    (wcat + 65536)[(long)hc * 256 + tid] = __float2bfloat16(a);
    if (tid == 0) {
        float s = bsl[g];
        #pragma unroll
        for (int d = 0; d < 32; ++d) s += bx[h * 32 + d] * wcol[d];
        bcomb[hc] = s;
    }
}

// ---------------------------------------------------------------------------
// Kernel 1 (MFMA, 8 waves / 512 thr): LN1 + GEMM + slice softmax (r19-proven).
// ---------------------------------------------------------------------------
__global__ __launch_bounds__(512, 4) void k1_mfma(
    const float* __restrict__ fx,
    const float* __restrict__ g1, const float* __restrict__ b1,
    const __hip_bfloat16* __restrict__ wcat,   // [512][256]
    const float* __restrict__ bfx, const float* __restrict__ bcomb,
    const float* __restrict__ temp,
    __hip_bfloat16* __restrict__ fxm_o, __hip_bfloat16* __restrict__ sw_o)
{
    __shared__ __align__(16) char lds[65536];
    const int tid = threadIdx.x;
    const int lane = tid & 63, wid = tid >> 6;   // 8 waves
    const long tok0 = (long)blockIdx.x * 64;
    const int col = lane & 15, kq = lane >> 4;
    const int swz = (col & 7) << 4;
    const int ep = ((kq * 16) ^ swz) & 48;
    const int e0 = (swz & 64) | ep;
    const int e1 = ((swz & 64) ^ 64) | ep;
    const int ab0 = col * 512 + e0, ab1 = col * 512 + e1;

    {
        const float4 gv = *reinterpret_cast<const float4*>(g1 + lane * 4);
        const float4 bv = *reinterpret_cast<const float4*>(b1 + lane * 4);
        #pragma unroll
        for (int tt = 0; tt < 8; ++tt) {
            const int r = wid * 8 + tt;
            const float4 v = *reinterpret_cast<const float4*>(fx + (tok0 + r) * 256 + lane * 4);
            float s = v.x + v.y + v.z + v.w;
            float s2 = v.x * v.x + v.y * v.y + v.z * v.z + v.w * v.w;
            #pragma unroll
            for (int off = 32; off; off >>= 1) {
                s  += __shfl_xor(s,  off);
                s2 += __shfl_xor(s2, off);
            }
            const float mean = s * (1.f / 256.f);
            const float rs = rsqrtf(s2 * (1.f / 256.f) - mean * mean + 1e-5f);
            short4v o;
            o[0] = f2bf((v.x - mean) * rs * gv.x + bv.x);
            o[1] = f2bf((v.y - mean) * rs * gv.y + bv.y);
            o[2] = f2bf((v.z - mean) * rs * gv.z + bv.z);
            o[3] = f2bf((v.w - mean) * rs * gv.w + bv.w);
            const int addr = r * 512 + ((lane * 8) ^ ((r & 7) << 4));
            *reinterpret_cast<short4v*>(lds + addr) = o;
        }
    }
    __syncthreads();

    const int n0 = wid * 64;
    f32x4 acc[4][4];
    #pragma unroll
    for (int mt = 0; mt < 4; ++mt)
        #pragma unroll
        for (int nt = 0; nt < 4; ++nt) acc[mt][nt] = (f32x4){0.f, 0.f, 0.f, 0.f};

    const short* wp = reinterpret_cast<const short*>(wcat) + (n0 + col) * 256 + kq * 8;
    #pragma unroll 2
    for (int j = 0; j < 4; ++j) {
        short8v a0[4], a1[4];
        #pragma unroll
        for (int mt = 0; mt < 4; ++mt) {
            a0[mt] = *reinterpret_cast<const short8v*>(lds + mt * 8192 + j * 128 + ab0);
            a1[mt] = *reinterpret_cast<const short8v*>(lds + mt * 8192 + j * 128 + ab1);
        }
        #pragma unroll
        for (int nt = 0; nt < 4; ++nt) {
            const short8v b0 = *reinterpret_cast<const short8v*>(wp + nt * 4096 + j * 64);
            const short8v b1 = *reinterpret_cast<const short8v*>(wp + nt * 4096 + j * 64 + 32);
            #pragma unroll
            for (int mt = 0; mt < 4; ++mt) {
                acc[mt][nt] = __builtin_amdgcn_mfma_f32_16x16x32_bf16(a0[mt], b0, acc[mt][nt], 0, 0, 0);
                acc[mt][nt] = __builtin_amdgcn_mfma_f32_16x16x32_bf16(a1[mt], b1, acc[mt][nt], 0, 0, 0);
            }
        }
    }
    __syncthreads();

    #pragma unroll
    for (int nt = 0; nt < 4; ++nt) {
        const int c = n0 + nt * 16 + col;
        const float bb = (c < 256) ? bfx[c] : bcomb[c - 256];
        #pragma unroll
        for (int mt = 0; mt < 4; ++mt) {
            #pragma unroll
            for (int r = 0; r < 4; ++r) {
                const int row = mt * 16 + kq * 4 + r;
                const int byte = row * 1024 + ((c * 2) ^ ((row & 7) << 4));
                *reinterpret_cast<short*>(lds + byte) = f2bf(acc[mt][nt][r] + bb);
            }
        }
    }
    __syncthreads();

    #pragma unroll
    for (int it = 0; it < 4; ++it) {
        const int idx = it * 512 + tid;
        const int row = idx >> 5, ch = idx & 31;
        const short8v val = *reinterpret_cast<const short8v*>(
            lds + row * 1024 + ((ch * 16) ^ ((row & 7) << 4)));
        *reinterpret_cast<short8v*>(
            reinterpret_cast<short*>(fxm_o) + (tok0 + row) * 256 + ch * 8) = val;
    }

    {
        const int t = tid >> 3, h = tid & 7;
        const float it_ = 1.f / temp[h];
        float lg[32];
        #pragma unroll
        for (int g = 0; g < 32; ++g) {
            const int byte = t * 1024 + (((256 + h * 32 + g) * 2) ^ ((t & 7) << 4));
            lg[g] = bf2f(*reinterpret_cast<const short*>(lds + byte)) * it_;
        }
        float mx = -1e30f;
        #pragma unroll
        for (int g = 0; g < 32; ++g) mx = fmaxf(mx, lg[g]);
        float ssum = 0.f;
        #pragma unroll
        for (int g = 0; g < 32; ++g) { lg[g] = __expf(lg[g] - mx); ssum += lg[g]; }
        const float inv = 1.f / ssum;
        #pragma unroll
        for (int g = 0; g < 32; ++g) {
            const int byte = t * 1024 + (((256 + h * 32 + g) * 2) ^ ((t & 7) << 4));
            *reinterpret_cast<short*>(lds + byte) = f2bf(lg[g] * inv);
        }
    }
    __syncthreads();

    #pragma unroll
    for (int it = 0; it < 4; ++it) {
        const int idx = it * 512 + tid;
        const int row = idx >> 5, ch = idx & 31;
        const short8v val = *reinterpret_cast<const short8v*>(
            lds + row * 1024 + ((512 + ch * 16) ^ ((row & 7) << 4)));
        *reinterpret_cast<short8v*>(
            reinterpret_cast<short*>(sw_o) + (tok0 + row) * 256 + ch * 8) = val;
    }
}

// ---------------------------------------------------------------------------
// Kernel 2 (8 waves): st partials — wave-local, barrier-free accumulation.
// ---------------------------------------------------------------------------
__global__ __launch_bounds__(512) void k2_st_partial(
    const __hip_bfloat16* __restrict__ fxm, const __hip_bfloat16* __restrict__ sw,
    float* __restrict__ pst, float* __restrict__ pn)
{
    __shared__ float psum[8][32][32];
    __shared__ float pns[8][32];
    const int tid = threadIdx.x, wid = tid >> 6, lane = tid & 63;
    const int blk = blockIdx.x;
    const int bh = blk >> 5, chunk = blk & 31;
    const int b = bh >> 3, h = bh & 7;
    const long rbase = (long)b * NTOK + (long)chunk * 1024 + wid * 128;
    const int gB = lane >> 3, dB = lane & 7;
    const short* sp = reinterpret_cast<const short*>(sw) + rbase * 256 + h * 32 + gB * 4;
    const short* fp = reinterpret_cast<const short*>(fxm) + rbase * 256 + h * 32 + dB * 4;

    float acc[4][4];
    float nacc[4];
    #pragma unroll
    for (int i = 0; i < 4; ++i) {
        nacc[i] = 0.f;
        #pragma unroll
        for (int j = 0; j < 4; ++j) acc[i][j] = 0.f;
    }

    #pragma unroll 4
    for (int r = 0; r < 128; ++r) {
        const short4v s4 = *reinterpret_cast<const short4v*>(sp + r * 256);
        const short4v f4 = *reinterpret_cast<const short4v*>(fp + r * 256);
        float sg[4], fd[4];
        #pragma unroll
        for (int i = 0; i < 4; ++i) { sg[i] = bf2f(s4[i]); fd[i] = bf2f(f4[i]); }
        #pragma unroll
        for (int gg = 0; gg < 4; ++gg) {
            nacc[gg] += sg[gg];
            #pragma unroll
            for (int dd = 0; dd < 4; ++dd) acc[gg][dd] += sg[gg] * fd[dd];
        }
    }

    #pragma unroll
    for (int gg = 0; gg < 4; ++gg) {
        #pragma unroll
        for (int dd = 0; dd < 4; ++dd)
            psum[wid][gB * 4 + gg][dB * 4 + dd] = acc[gg][dd];
        if (dB == 0) pns[wid][gB * 4 + gg] = nacc[gg];
    }
    __syncthreads();

    for (int i = tid; i < 1024; i += 512) {
        const int g = i >> 5, d = i & 31;
        float s = 0.f;
        #pragma unroll
        for (int w = 0; w < 8; ++w) s += psum[w][g][d];
        pst[(long)blk * 1024 + i] = s;
    }
    if (tid < 32) {
        float s = 0.f;
        #pragma unroll
        for (int w = 0; w < 8; ++w) s += pns[w][tid];
        pn[blk * 32 + tid] = s;
    }
}

// ---------------------------------------------------------------------------
// Kernel 3: reduce partials -> st; slice self-attn + cross-attn -> ostT (bf16).
// ---------------------------------------------------------------------------
__global__ __launch_bounds__(256) void k3_slice_attn(
    const float* __restrict__ pst, const float* __restrict__ pn,
    const float* __restrict__ ctx,
    const float* __restrict__ Wq, const float* __restrict__ Wk, const float* __restrict__ Wv,
    const float* __restrict__ Wcq, const float* __restrict__ bcq,
    const float* __restrict__ Wck, const float* __restrict__ bck,
    const float* __restrict__ Wcv, const float* __restrict__ bcv,
    const float* __restrict__ mix, __hip_bfloat16* __restrict__ ostT_o)
{
    __shared__ float st[1024], qm[1024], km[1024], vm[1024], cqm[1024];
    __shared__ float ckm[2048], cvm[2048], attn[2048], stok[1024], nb[32];
    const int tid = threadIdx.x;
    const int bh = blockIdx.x;

    if (tid < 32) {
        float s = 0.f;
        for (int c = 0; c < 32; ++c) s += pn[(bh * 32 + c) * 32 + tid];
        nb[tid] = s;
    }
    __syncthreads();
    for (int i = tid; i < 1024; i += 256) {
        float s = 0.f;
        for (int c = 0; c < 32; ++c) s += pst[(long)(bh * 32 + c) * 1024 + i];
        st[i] = s / (nb[i >> 5] + 1e-5f);
    }
    __syncthreads();

    for (int i = tid; i < 1024; i += 256) {
        const int g = i >> 5, d = i & 31;
        float aq = 0.f, ak = 0.f, av = 0.f, ac = bcq[d];
        #pragma unroll
        for (int e = 0; e < 32; ++e) {
            const float s = st[g * 32 + e];
            aq += s * Wq[e * 32 + d];
            ak += s * Wk[e * 32 + d];
            av += s * Wv[e * 32 + d];
            ac += s * Wcq[e * 32 + d];
        }
        qm[i] = aq; km[i] = ak; vm[i] = av; cqm[i] = ac;
    }
    const float* cbp = ctx + (long)bh * (NSC * NDC);
    for (int i = tid; i < 2048; i += 256) {
        const int s_ = i >> 5, d = i & 31;
        float w1 = bck[d], w2 = bcv[d];
        #pragma unroll
        for (int e = 0; e < 32; ++e) {
            const float cval = cbp[s_ * 32 + e];
            w1 += cval * Wck[e * 32 + d];
            w2 += cval * Wcv[e * 32 + d];
        }
        ckm[i] = w1; cvm[i] = w2;
    }
    __syncthreads();

    const float scale = 0.17677669529663687f;
    for (int i = tid; i < 1024; i += 256) {
        const int g = i >> 5, m = i & 31;
        float a = 0.f;
        #pragma unroll
        for (int d = 0; d < 32; ++d) a += qm[g * 32 + d] * km[m * 32 + d];
        attn[i] = a * scale;
    }
    __syncthreads();
    if (tid < 32) {
        float mx = -1e30f;
        for (int m = 0; m < 32; ++m) mx = fmaxf(mx, attn[tid * 32 + m]);
        float s = 0.f;
        for (int m = 0; m < 32; ++m) { const float e = expf(attn[tid * 32 + m] - mx); attn[tid * 32 + m] = e; s += e; }
        const float inv = 1.f / s;
        for (int m = 0; m < 32; ++m) attn[tid * 32 + m] *= inv;
    }
    __syncthreads();
    for (int i = tid; i < 1024; i += 256) {
        const int g = i >> 5, d = i & 31;
        float a = 0.f;
        #pragma unroll
        for (int m = 0; m < 32; ++m) a += attn[g * 32 + m] * vm[m * 32 + d];
        stok[i] = a;
    }
    __syncthreads();
    for (int i = tid; i < 2048; i += 256) {
        const int g = i >> 6, s_ = i & 63;
        float a = 0.f;
        #pragma unroll
        for (int d = 0; d < 32; ++d) a += cqm[g * 32 + d] * ckm[s_ * 32 + d];
        attn[i] = a * scale;
    }
    __syncthreads();
    if (tid < 32) {
        float mx = -1e30f;
        for (int m = 0; m < 64; ++m) mx = fmaxf(mx, attn[tid * 64 + m]);
        float s = 0.f;
        for (int m = 0; m < 64; ++m) { const float e = expf(attn[tid * 64 + m] - mx); attn[tid * 64 + m] = e; s += e; }
        const float inv = 1.f / s;
        for (int m = 0; m < 64; ++m) attn[tid * 64 + m] *= inv;
    }
    __syncthreads();
    const float mw = 1.f / (1.f + expf(-mix[0]));
    for (int i = tid; i < 1024; i += 256) {
        const int g = i >> 5, d = i & 31;
        float a = 0.f;
        #pragma unroll
        for (int s_ = 0; s_ < 64; ++s_) a += attn[g * 64 + s_] * cvm[s_ * 32 + d];
        const float val = mw * stok[i] + (1.f - mw) * a;
        ostT_o[(long)bh * 1024 + d * 32 + g] = __float2bfloat16(val);
    }
}

// ---------------------------------------------------------------------------
// Kernel 45 (fused, 8 waves, 64KB LDS): de-slice + Wout GEMM + LN2 + MLP.
// r19-proven: bounds(512,4) (64-reg clamp + mild spill is the optimal point
// of the register/occupancy bind), A2 double-buffered chunk=128, RMW epilogue.
// ---------------------------------------------------------------------------
__global__ __launch_bounds__(512, 4) void k45_fused(
    const __hip_bfloat16* __restrict__ sw, const __hip_bfloat16* __restrict__ ostT,
    const __hip_bfloat16* __restrict__ woutt, const float* __restrict__ bout,
    const float* __restrict__ fx,
    const float* __restrict__ g2, const float* __restrict__ b2,
    const __hip_bfloat16* __restrict__ w1t, const float* __restrict__ bm1,
    const __hip_bfloat16* __restrict__ w2t, const float* __restrict__ bm2,
    float* __restrict__ out)
{
    __shared__ __align__(16) char lds[65536];
    const int tid = threadIdx.x;
    const int lane = tid & 63, wid = tid >> 6;   // 8 waves
    const long tok0 = (long)blockIdx.x * 64;
    const int b = (int)(tok0 >> 15);
    const int col = lane & 15, kq = lane >> 4;
    const int swz = (col & 7) << 4;
    const int ep = ((kq * 16) ^ swz) & 48;
    const int e0 = (swz & 64) | ep;
    const int e1 = ((swz & 64) ^ 64) | ep;
    const int ab0 = col * 512 + e0, ab1 = col * 512 + e1;
    const int cb0 = col * 256 + e0, cb1 = col * 256 + e1;

    // ---- stage sw -> [0,32K) bf16 swizzled ----
    #pragma unroll
    for (int it = 0; it < 4; ++it) {
        const int idx = it * 512 + tid;
        const int row = idx >> 5, ch = idx & 31;
        const short8v val = *reinterpret_cast<const short8v*>(
            reinterpret_cast<const short*>(sw) + (tok0 + row) * 256 + ch * 8);
        *reinterpret_cast<short8v*>(lds + row * 512 + ((ch * 16) ^ ((row & 7) << 4))) = val;
    }
    __syncthreads();

    // ---- de-slice via MFMA: wave handles head h = wid ----
    {
        f32x4 accal[4][2];
        const int abh = col * 512 + (((wid * 64) | (kq * 16)) ^ swz);
        short8v a[4];
        #pragma unroll
        for (int mt = 0; mt < 4; ++mt)
            a[mt] = *reinterpret_cast<const short8v*>(lds + mt * 8192 + abh);
        #pragma unroll
        for (int nt = 0; nt < 2; ++nt) {
            const int d = nt * 16 + col;
            const short8v bfr = *reinterpret_cast<const short8v*>(
                reinterpret_cast<const short*>(ostT) + ((b * 8 + wid) * 32 + d) * 32 + kq * 8);
            #pragma unroll
            for (int mt = 0; mt < 4; ++mt) {
                accal[mt][nt] = (f32x4){0.f, 0.f, 0.f, 0.f};
                accal[mt][nt] = __builtin_amdgcn_mfma_f32_16x16x32_bf16(
                    a[mt], bfr, accal[mt][nt], 0, 0, 0);
            }
        }
        #pragma unroll
        for (int nt = 0; nt < 2; ++nt) {
            const int cc = wid * 32 + nt * 16 + col;
            #pragma unroll
            for (int mt = 0; mt < 4; ++mt) {
                #pragma unroll
                for (int r = 0; r < 4; ++r) {
                    const int row = mt * 16 + kq * 4 + r;
                    const int byte = 32768 + row * 512 + ((cc * 2) ^ ((row & 7) << 4));
                    *reinterpret_cast<short*>(lds + byte) = f2bf(accal[mt][nt][r]);
                }
            }
        }
    }
    __syncthreads();

    // ---- Wout GEMM ----
    f32x4 acc[4][2];
    #pragma unroll
    for (int mt = 0; mt < 4; ++mt)
        #pragma unroll
        for (int nt = 0; nt < 2; ++nt) acc[mt][nt] = (f32x4){0.f, 0.f, 0.f, 0.f};

    {
        const short* wp = reinterpret_cast<const short*>(woutt) + (wid * 32 + col) * 256 + kq * 8;
        #pragma unroll 2
        for (int j = 0; j < 4; ++j) {
            short8v a0[4], a1[4];
            #pragma unroll
            for (int mt = 0; mt < 4; ++mt) {
                a0[mt] = *reinterpret_cast<const short8v*>(lds + 32768 + mt * 8192 + j * 128 + ab0);
                a1[mt] = *reinterpret_cast<const short8v*>(lds + 32768 + mt * 8192 + j * 128 + ab1);
            }
            #pragma unroll
            for (int nt = 0; nt < 2; ++nt) {
                const short8v b0 = *reinterpret_cast<const short8v*>(wp + nt * 4096 + j * 64);
                const short8v b1 = *reinterpret_cast<const short8v*>(wp + nt * 4096 + j * 64 + 32);
                #pragma unroll
                for (int mt = 0; mt < 4; ++mt) {
                    acc[mt][nt] = __builtin_amdgcn_mfma_f32_16x16x32_bf16(a0[mt], b0, acc[mt][nt], 0, 0, 0);
                    acc[mt][nt] = __builtin_amdgcn_mfma_f32_16x16x32_bf16(a1[mt], b1, acc[mt][nt], 0, 0, 0);
                }
            }
        }
    }

    // ---- stage attn output (acc+bout) as f32 [64][256] ----
    __syncthreads();
    float* lf = reinterpret_cast<float*>(lds);
    #pragma unroll
    for (int nt = 0; nt < 2; ++nt) {
        const int c = wid * 32 + nt * 16 + col;
        const float bb = bout[c];
        #pragma unroll
        for (int mt = 0; mt < 4; ++mt) {
            #pragma unroll
            for (int r = 0; r < 4; ++r) {
                const int row = mt * 16 + kq * 4 + r;
                lf[row * 256 + c] = acc[mt][nt][r] + bb;
            }
        }
    }
    __syncthreads();

    // ---- LN2: read attn tile + fx; store out_attn to global NOW ----
    short4v aout[8];
    {
        const float4 gv = *reinterpret_cast<const float4*>(g2 + lane * 4);
        const float4 bv = *reinterpret_cast<const float4*>(b2 + lane * 4);
        #pragma unroll
        for (int tt = 0; tt < 8; ++tt) {
            const int r = wid * 8 + tt;
            const float4 l4 = *reinterpret_cast<const float4*>(lf + r * 256 + lane * 4);
            const float4 f4 = *reinterpret_cast<const float4*>(fx + (tok0 + r) * 256 + lane * 4);
            float4 oa;
            oa.x = l4.x + f4.x; oa.y = l4.y + f4.y;
            oa.z = l4.z + f4.z; oa.w = l4.w + f4.w;
            *reinterpret_cast<float4*>(out + (tok0 + r) * 256 + lane * 4) = oa;
            float s = oa.x + oa.y + oa.z + oa.w;
            float s2 = oa.x * oa.x + oa.y * oa.y + oa.z * oa.z + oa.w * oa.w;
            #pragma unroll
            for (int off = 32; off; off >>= 1) {
                s  += __shfl_xor(s,  off);
                s2 += __shfl_xor(s2, off);
            }
            const float mean = s * (1.f / 256.f);
            const float rs = rsqrtf(s2 * (1.f / 256.f) - mean * mean + 1e-5f);
            aout[tt][0] = f2bf((oa.x - mean) * rs * gv.x + bv.x);
            aout[tt][1] = f2bf((oa.y - mean) * rs * gv.y + bv.y);
            aout[tt][2] = f2bf((oa.z - mean) * rs * gv.z + bv.z);
            aout[tt][3] = f2bf((oa.w - mean) * rs * gv.w + bv.w);
        }
    }
    __syncthreads();
    #pragma unroll
    for (int tt = 0; tt < 8; ++tt) {
        const int r = wid * 8 + tt;
        const int addr = r * 512 + ((lane * 8) ^ ((r & 7) << 4));
        *reinterpret_cast<short4v*>(lds + addr) = aout[tt];
    }
    __syncthreads();

    // ---- MLP: chunk=128, A2 double-buffered (16KB each), 1 barrier/chunk ----
    const int n0 = wid * 32;
    const int h0 = wid * 16;
    const short* w1s = reinterpret_cast<const short*>(w1t) + (h0 + col) * 256 + kq * 8;
    const short* w2s = reinterpret_cast<const short*>(w2t) + (n0 + col) * 1024 + kq * 8;

    f32x4 accO[4][2];
    #pragma unroll
    for (int mt = 0; mt < 4; ++mt)
        #pragma unroll
        for (int nt = 0; nt < 2; ++nt) accO[mt][nt] = (f32x4){0.f, 0.f, 0.f, 0.f};

    for (int ch = 0; ch < 8; ++ch) {
        const int abuf = 32768 + (ch & 1) * 16384;

        f32x4 accP[4];
        #pragma unroll
        for (int mt = 0; mt < 4; ++mt) accP[mt] = (f32x4){0.f, 0.f, 0.f, 0.f};

        #pragma unroll 1
        for (int j = 0; j < 4; ++j) {
            const short8v b0 = *reinterpret_cast<const short8v*>(w1s + ch * 32768 + j * 64);
            const short8v b1 = *reinterpret_cast<const short8v*>(w1s + ch * 32768 + j * 64 + 32);
            #pragma unroll
            for (int mt = 0; mt < 4; ++mt) {
                const short8v a0 = *reinterpret_cast<const short8v*>(lds + mt * 8192 + j * 128 + ab0);
                const short8v a1 = *reinterpret_cast<const short8v*>(lds + mt * 8192 + j * 128 + ab1);
                accP[mt] = __builtin_amdgcn_mfma_f32_16x16x32_bf16(a0, b0, accP[mt], 0, 0, 0);
                accP[mt] = __builtin_amdgcn_mfma_f32_16x16x32_bf16(a1, b1, accP[mt], 0, 0, 0);
            }
        }

        {
            const float b1v = bm1[ch * 128 + h0 + col];
            const int k2i2 = (h0 + col) * 2;
            #pragma unroll
            for (int mt = 0; mt < 4; ++mt) {
                #pragma unroll
                for (int r = 0; r < 4; ++r) {
                    float m = accP[mt][r] + b1v;
                    const float u = __builtin_fmaf(0.044715f * m, m * m, m);
                    const float e = __expf(-1.5957691216057308f * u);
                    m = m * __builtin_amdgcn_rcpf(1.f + e);
                    const int row = mt * 16 + kq * 4 + r;
                    const int byte = abuf + row * 256 + (k2i2 ^ ((row & 7) << 4));
                    *reinterpret_cast<short*>(lds + byte) = f2bf(m);
                }
            }
        }
        __syncthreads();

        #pragma unroll 1
        for (int j = 0; j < 2; ++j) {
            short8v b20[2], b21[2];
            #pragma unroll
            for (int nt = 0; nt < 2; ++nt) {
                b20[nt] = *reinterpret_cast<const short8v*>(w2s + nt * 16384 + ch * 128 + j * 64);
                b21[nt] = *reinterpret_cast<const short8v*>(w2s + nt * 16384 + ch * 128 + j * 64 + 32);
            }
            #pragma unroll
            for (int mt = 0; mt < 4; ++mt) {
                const short8v x0 = *reinterpret_cast<const short8v*>(lds + abuf + mt * 4096 + j * 128 + cb0);
                const short8v x1 = *reinterpret_cast<const short8v*>(lds + abuf + mt * 4096 + j * 128 + cb1);
                #pragma unroll
                for (int nt = 0; nt < 2; ++nt) {
                    accO[mt][nt] = __builtin_amdgcn_mfma_f32_16x16x32_bf16(x0, b20[nt], accO[mt][nt], 0, 0, 0);
                    accO[mt][nt] = __builtin_amdgcn_mfma_f32_16x16x32_bf16(x1, b21[nt], accO[mt][nt], 0, 0, 0);
                }
            }
        }
    }

    // ---- epilogue: accO+bm2 -> lf; out += mlp (RMW) ----
    __syncthreads();
    #pragma unroll
    for (int nt = 0; nt < 2; ++nt) {
        const int c = n0 + nt * 16 + col;
        const float b2v = bm2[c];
        #pragma unroll
        for (int mt = 0; mt < 4; ++mt) {
            #pragma unroll
            for (int r = 0; r < 4; ++r) {
                const int row = mt * 16 + kq * 4 + r;
                lf[row * 256 + c] = accO[mt][nt][r] + b2v;
            }
        }
    }
    __syncthreads();
    #pragma unroll
    for (int tt = 0; tt < 8; ++tt) {
        const int r = wid * 8 + tt;
        const float4 m4 = *reinterpret_cast<const float4*>(lf + r * 256 + lane * 4);
        const long gidx = (tok0 + r) * 256 + lane * 4;
        const float4 oa = *reinterpret_cast<const float4*>(out + gidx);
        float4 o;
        o.x = oa.x + m4.x; o.y = oa.y + m4.y;
        o.z = oa.z + m4.z; o.w = oa.w + m4.w;
        *reinterpret_cast<float4*>(out + gidx) = o;
    }
}

// ---------------------------------------------------------------------------
extern "C" void kernel_launch(void* const* d_in, const int* in_sizes, int n_in,
                              void* d_out, int out_size, void* d_ws, size_t ws_size,
                              hipStream_t stream)
{
    const float* fx   = (const float*)d_in[0];
    const float* ctx  = (const float*)d_in[1];
    const float* g1   = (const float*)d_in[2];
    const float* b1   = (const float*)d_in[3];
    const float* Wfx  = (const float*)d_in[4];
    const float* bfx  = (const float*)d_in[5];
    const float* Wx   = (const float*)d_in[6];
    const float* bx   = (const float*)d_in[7];
    const float* Wsl  = (const float*)d_in[8];
    const float* bsl  = (const float*)d_in[9];
    const float* temp = (const float*)d_in[10];
    const float* Wq   = (const float*)d_in[11];
    const float* Wk   = (const float*)d_in[12];
    const float* Wv   = (const float*)d_in[13];
    const float* Wcq  = (const float*)d_in[14];
    const float* bcq  = (const float*)d_in[15];
    const float* Wck  = (const float*)d_in[16];
    const float* bck  = (const float*)d_in[17];
    const float* Wcv  = (const float*)d_in[18];
    const float* bcv  = (const float*)d_in[19];
    const float* mix  = (const float*)d_in[20];
    const float* Wout = (const float*)d_in[21];
    const float* bout = (const float*)d_in[22];
    const float* g2   = (const float*)d_in[23];
    const float* b2   = (const float*)d_in[24];
    const float* Wm1  = (const float*)d_in[25];
    const float* bm1  = (const float*)d_in[26];
    const float* Wm2  = (const float*)d_in[27];
    const float* bm2  = (const float*)d_in[28];
    float* out = (float*)d_out;

    char* ws = (char*)d_ws;
    __hip_bfloat16* fxm  = (__hip_bfloat16*)ws;                         // 32MB
    __hip_bfloat16* sw   = (__hip_bfloat16*)(ws + (size_t)33554432);    // 32MB
    float* pst = (float*)(ws + (size_t)67108864);                       // 2MB
    float* pn  = (float*)(ws + (size_t)69206016);                       // 64KB
    __hip_bfloat16* ostT  = (__hip_bfloat16*)(ws + (size_t)69271552);   // 32KB
    __hip_bfloat16* wcat  = (__hip_bfloat16*)(ws + (size_t)69304320);   // 256KB [Wfx^T; Wcomb^T]
    __hip_bfloat16* woutt = (__hip_bfloat16*)(ws + (size_t)69566464);   // 128KB
    __hip_bfloat16* w1t   = (__hip_bfloat16*)(ws + (size_t)69697536);   // 512KB
    __hip_bfloat16* w2t   = (__hip_bfloat16*)(ws + (size_t)70221824);   // 512KB
    float* bcomb          = (float*)(ws + (size_t)70746112);            // 1KB

    kprep<<<896, 256, 0, stream>>>(Wfx, wcat, Wout, woutt, Wm1, w1t, Wm2, w2t,
                                   Wx, bx, Wsl, bsl, bcomb);

    k1_mfma<<<1024, 512, 0, stream>>>(fx, g1, b1, wcat, bfx, bcomb, temp,
                                      fxm, sw);
    k2_st_partial<<<512, 512, 0, stream>>>(fxm, sw, pst, pn);
    k3_slice_attn<<<16, 256, 0, stream>>>(pst, pn, ctx, Wq, Wk, Wv,
                                          Wcq, bcq, Wck, bck, Wcv, bcv, mix, ostT);
    k45_fused<<<1024, 512, 0, stream>>>(sw, ostT, woutt, bout, fx,
                                        g2, b2, w1t, bm1, w2t, bm2, out);
}

// Round 25
// 307.644 us; speedup vs baseline: 1.0770x; 1.0026x over previous
//
#include <hip/hip_runtime.h>
#include <hip/hip_bf16.h>

#define BATCH 2
#define NTOK  32768
#define CH    256
#define NH    8
#define HDIM  32
#define NG    32
#define NSC   64
#define NDC   32

typedef __attribute__((ext_vector_type(8))) short short8v;
typedef __attribute__((ext_vector_type(4))) short short4v;
typedef __attribute__((ext_vector_type(4))) float f32x4;

static __device__ __forceinline__ short f2bf(float f) {
    __hip_bfloat16 h = __float2bfloat16(f);
    return __builtin_bit_cast(short, h);
}
static __device__ __forceinline__ float bf2f(short s) {
    return __bfloat162float(__builtin_bit_cast(__hip_bfloat16, s));
}

// ---------------------------------------------------------------------------
// Prep kernel: 4 weight transposes (blocks 0-639) + kcomb (blocks 640-895).
// ---------------------------------------------------------------------------
static __device__ __forceinline__ void transpose_tile(
    const float* __restrict__ in, __hip_bfloat16* __restrict__ out,
    int K, int N, int blk, int tid)
{
    __shared__ float t[32][33];
    const int nb = N >> 5;
    const int bk = blk / nb;
    const int bn = blk % nb;
    const int c = tid & 31, r0 = tid >> 5;
    #pragma unroll
    for (int i = 0; i < 4; ++i) {
        const int r = r0 + i * 8;
        t[r][c] = in[(long)(bk * 32 + r) * N + bn * 32 + c];
    }
    __syncthreads();
    #pragma unroll
    for (int i = 0; i < 4; ++i) {
        const int r = r0 + i * 8;
        out[(long)(bn * 32 + r) * K + bk * 32 + c] = __float2bfloat16(t[c][r]);
    }
}

__global__ __launch_bounds__(256) void kprep(
    const float* __restrict__ Wfx, __hip_bfloat16* __restrict__ wcat,
    const float* __restrict__ Wout, __hip_bfloat16* __restrict__ woutt,
    const float* __restrict__ Wm1, __hip_bfloat16* __restrict__ w1t,
    const float* __restrict__ Wm2, __hip_bfloat16* __restrict__ w2t,
    const float* __restrict__ Wx, const float* __restrict__ bx,
    const float* __restrict__ Wsl, const float* __restrict__ bsl,
    float* __restrict__ bcomb)
{
    const int b = blockIdx.x, tid = threadIdx.x;
    if (b < 64)       { transpose_tile(Wfx,  wcat,  256, 256,  b,       tid); return; }
    else if (b < 128) { transpose_tile(Wout, woutt, 256, 256,  b - 64,  tid); return; }
    else if (b < 384) { transpose_tile(Wm1,  w1t,   256, 1024, b - 128, tid); return; }
    else if (b < 640) { transpose_tile(Wm2,  w2t,   1024, 256, b - 384, tid); return; }
    __shared__ float wcol[32];
    const int hc = b - 640;
    const int h = hc >> 5, g = hc & 31;
    if (tid < 32) wcol[tid] = Wsl[tid * 32 + g];
    __syncthreads();
    float a = 0.f;
    #pragma unroll
    for (int d = 0; d < 32; ++d) a += Wx[tid * 256 + h * 32 + d] * wcol[d];
    (wcat + 65536)[(long)hc * 256 + tid] = __float2bfloat16(a);
    if (tid == 0) {
        float s = bsl[g];
        #pragma unroll
        for (int d = 0; d < 32; ++d) s += bx[h * 32 + d] * wcol[d];
        bcomb[hc] = s;
    }
}

// ---------------------------------------------------------------------------
// Kernel 1 (MFMA, 8 waves / 512 thr): LN1 + GEMM + slice softmax (r19-proven).
// ---------------------------------------------------------------------------
__global__ __launch_bounds__(512, 4) void k1_mfma(
    const float* __restrict__ fx,
    const float* __restrict__ g1, const float* __restrict__ b1,
    const __hip_bfloat16* __restrict__ wcat,   // [512][256]
    const float* __restrict__ bfx, const float* __restrict__ bcomb,
    const float* __restrict__ temp,
    __hip_bfloat16* __restrict__ fxm_o, __hip_bfloat16* __restrict__ sw_o)
{
    __shared__ __align__(16) char lds[65536];
    const int tid = threadIdx.x;
    const int lane = tid & 63, wid = tid >> 6;   // 8 waves
    const long tok0 = (long)blockIdx.x * 64;
    const int col = lane & 15, kq = lane >> 4;
    const int swz = (col & 7) << 4;
    const int ep = ((kq * 16) ^ swz) & 48;
    const int e0 = (swz & 64) | ep;
    const int e1 = ((swz & 64) ^ 64) | ep;
    const int ab0 = col * 512 + e0, ab1 = col * 512 + e1;

    {
        const float4 gv = *reinterpret_cast<const float4*>(g1 + lane * 4);
        const float4 bv = *reinterpret_cast<const float4*>(b1 + lane * 4);
        #pragma unroll
        for (int tt = 0; tt < 8; ++tt) {
            const int r = wid * 8 + tt;
            const float4 v = *reinterpret_cast<const float4*>(fx + (tok0 + r) * 256 + lane * 4);
            float s = v.x + v.y + v.z + v.w;
            float s2 = v.x * v.x + v.y * v.y + v.z * v.z + v.w * v.w;
            #pragma unroll
            for (int off = 32; off; off >>= 1) {
                s  += __shfl_xor(s,  off);
                s2 += __shfl_xor(s2, off);
            }
            const float mean = s * (1.f / 256.f);
            const float rs = rsqrtf(s2 * (1.f / 256.f) - mean * mean + 1e-5f);
            short4v o;
            o[0] = f2bf((v.x - mean) * rs * gv.x + bv.x);
            o[1] = f2bf((v.y - mean) * rs * gv.y + bv.y);
            o[2] = f2bf((v.z - mean) * rs * gv.z + bv.z);
            o[3] = f2bf((v.w - mean) * rs * gv.w + bv.w);
            const int addr = r * 512 + ((lane * 8) ^ ((r & 7) << 4));
            *reinterpret_cast<short4v*>(lds + addr) = o;
        }
    }
    __syncthreads();

    const int n0 = wid * 64;
    f32x4 acc[4][4];
    #pragma unroll
    for (int mt = 0; mt < 4; ++mt)
        #pragma unroll
        for (int nt = 0; nt < 4; ++nt) acc[mt][nt] = (f32x4){0.f, 0.f, 0.f, 0.f};

    const short* wp = reinterpret_cast<const short*>(wcat) + (n0 + col) * 256 + kq * 8;
    #pragma unroll 2
    for (int j = 0; j < 4; ++j) {
        short8v a0[4], a1[4];
        #pragma unroll
        for (int mt = 0; mt < 4; ++mt) {
            a0[mt] = *reinterpret_cast<const short8v*>(lds + mt * 8192 + j * 128 + ab0);
            a1[mt] = *reinterpret_cast<const short8v*>(lds + mt * 8192 + j * 128 + ab1);
        }
        #pragma unroll
        for (int nt = 0; nt < 4; ++nt) {
            const short8v b0 = *reinterpret_cast<const short8v*>(wp + nt * 4096 + j * 64);
            const short8v b1 = *reinterpret_cast<const short8v*>(wp + nt * 4096 + j * 64 + 32);
            #pragma unroll
            for (int mt = 0; mt < 4; ++mt) {
                acc[mt][nt] = __builtin_amdgcn_mfma_f32_16x16x32_bf16(a0[mt], b0, acc[mt][nt], 0, 0, 0);
                acc[mt][nt] = __builtin_amdgcn_mfma_f32_16x16x32_bf16(a1[mt], b1, acc[mt][nt], 0, 0, 0);
            }
        }
    }
    __syncthreads();

    #pragma unroll
    for (int nt = 0; nt < 4; ++nt) {
        const int c = n0 + nt * 16 + col;
        const float bb = (c < 256) ? bfx[c] : bcomb[c - 256];
        #pragma unroll
        for (int mt = 0; mt < 4; ++mt) {
            #pragma unroll
            for (int r = 0; r < 4; ++r) {
                const int row = mt * 16 + kq * 4 + r;
                const int byte = row * 1024 + ((c * 2) ^ ((row & 7) << 4));
                *reinterpret_cast<short*>(lds + byte) = f2bf(acc[mt][nt][r] + bb);
            }
        }
    }
    __syncthreads();

    #pragma unroll
    for (int it = 0; it < 4; ++it) {
        const int idx = it * 512 + tid;
        const int row = idx >> 5, ch = idx & 31;
        const short8v val = *reinterpret_cast<const short8v*>(
            lds + row * 1024 + ((ch * 16) ^ ((row & 7) << 4)));
        *reinterpret_cast<short8v*>(
            reinterpret_cast<short*>(fxm_o) + (tok0 + row) * 256 + ch * 8) = val;
    }

    {
        const int t = tid >> 3, h = tid & 7;
        const float it_ = 1.f / temp[h];
        float lg[32];
        #pragma unroll
        for (int g = 0; g < 32; ++g) {
            const int byte = t * 1024 + (((256 + h * 32 + g) * 2) ^ ((t & 7) << 4));
            lg[g] = bf2f(*reinterpret_cast<const short*>(lds + byte)) * it_;
        }
        float mx = -1e30f;
        #pragma unroll
        for (int g = 0; g < 32; ++g) mx = fmaxf(mx, lg[g]);
        float ssum = 0.f;
        #pragma unroll
        for (int g = 0; g < 32; ++g) { lg[g] = __expf(lg[g] - mx); ssum += lg[g]; }
        const float inv = 1.f / ssum;
        #pragma unroll
        for (int g = 0; g < 32; ++g) {
            const int byte = t * 1024 + (((256 + h * 32 + g) * 2) ^ ((t & 7) << 4));
            *reinterpret_cast<short*>(lds + byte) = f2bf(lg[g] * inv);
        }
    }
    __syncthreads();

    #pragma unroll
    for (int it = 0; it < 4; ++it) {
        const int idx = it * 512 + tid;
        const int row = idx >> 5, ch = idx & 31;
        const short8v val = *reinterpret_cast<const short8v*>(
            lds + row * 1024 + ((512 + ch * 16) ^ ((row & 7) << 4)));
        *reinterpret_cast<short8v*>(
            reinterpret_cast<short*>(sw_o) + (tok0 + row) * 256 + ch * 8) = val;
    }
}

// ---------------------------------------------------------------------------
// Kernel 2 (8 waves): st partials — wave-local, barrier-free accumulation.
// ---------------------------------------------------------------------------
__global__ __launch_bounds__(512) void k2_st_partial(
    const __hip_bfloat16* __restrict__ fxm, const __hip_bfloat16* __restrict__ sw,
    float* __restrict__ pst, float* __restrict__ pn)
{
    __shared__ float psum[8][32][32];
    __shared__ float pns[8][32];
    const int tid = threadIdx.x, wid = tid >> 6, lane = tid & 63;
    const int blk = blockIdx.x;
    const int bh = blk >> 5, chunk = blk & 31;
    const int b = bh >> 3, h = bh & 7;
    const long rbase = (long)b * NTOK + (long)chunk * 1024 + wid * 128;
    const int gB = lane >> 3, dB = lane & 7;
    const short* sp = reinterpret_cast<const short*>(sw) + rbase * 256 + h * 32 + gB * 4;
    const short* fp = reinterpret_cast<const short*>(fxm) + rbase * 256 + h * 32 + dB * 4;

    float acc[4][4];
    float nacc[4];
    #pragma unroll
    for (int i = 0; i < 4; ++i) {
        nacc[i] = 0.f;
        #pragma unroll
        for (int j = 0; j < 4; ++j) acc[i][j] = 0.f;
    }

    #pragma unroll 4
    for (int r = 0; r < 128; ++r) {
        const short4v s4 = *reinterpret_cast<const short4v*>(sp + r * 256);
        const short4v f4 = *reinterpret_cast<const short4v*>(fp + r * 256);
        float sg[4], fd[4];
        #pragma unroll
        for (int i = 0; i < 4; ++i) { sg[i] = bf2f(s4[i]); fd[i] = bf2f(f4[i]); }
        #pragma unroll
        for (int gg = 0; gg < 4; ++gg) {
            nacc[gg] += sg[gg];
            #pragma unroll
            for (int dd = 0; dd < 4; ++dd) acc[gg][dd] += sg[gg] * fd[dd];
        }
    }

    #pragma unroll
    for (int gg = 0; gg < 4; ++gg) {
        #pragma unroll
        for (int dd = 0; dd < 4; ++dd)
            psum[wid][gB * 4 + gg][dB * 4 + dd] = acc[gg][dd];
        if (dB == 0) pns[wid][gB * 4 + gg] = nacc[gg];
    }
    __syncthreads();

    for (int i = tid; i < 1024; i += 512) {
        const int g = i >> 5, d = i & 31;
        float s = 0.f;
        #pragma unroll
        for (int w = 0; w < 8; ++w) s += psum[w][g][d];
        pst[(long)blk * 1024 + i] = s;
    }
    if (tid < 32) {
        float s = 0.f;
        #pragma unroll
        for (int w = 0; w < 8; ++w) s += pns[w][tid];
        pn[blk * 32 + tid] = s;
    }
}

// ---------------------------------------------------------------------------
// Kernel 3: reduce partials -> st; slice self-attn + cross-attn -> ostT (bf16).
// ---------------------------------------------------------------------------
__global__ __launch_bounds__(256) void k3_slice_attn(
    const float* __restrict__ pst, const float* __restrict__ pn,
    const float* __restrict__ ctx,
    const float* __restrict__ Wq, const float* __restrict__ Wk, const float* __restrict__ Wv,
    const float* __restrict__ Wcq, const float* __restrict__ bcq,
    const float* __restrict__ Wck, const float* __restrict__ bck,
    const float* __restrict__ Wcv, const float* __restrict__ bcv,
    const float* __restrict__ mix, __hip_bfloat16* __restrict__ ostT_o)
{
    __shared__ float st[1024], qm[1024], km[1024], vm[1024], cqm[1024];
    __shared__ float ckm[2048], cvm[2048], attn[2048], stok[1024], nb[32];
    const int tid = threadIdx.x;
    const int bh = blockIdx.x;

    if (tid < 32) {
        float s = 0.f;
        for (int c = 0; c < 32; ++c) s += pn[(bh * 32 + c) * 32 + tid];
        nb[tid] = s;
    }
    __syncthreads();
    for (int i = tid; i < 1024; i += 256) {
        float s = 0.f;
        for (int c = 0; c < 32; ++c) s += pst[(long)(bh * 32 + c) * 1024 + i];
        st[i] = s / (nb[i >> 5] + 1e-5f);
    }
    __syncthreads();

    for (int i = tid; i < 1024; i += 256) {
        const int g = i >> 5, d = i & 31;
        float aq = 0.f, ak = 0.f, av = 0.f, ac = bcq[d];
        #pragma unroll
        for (int e = 0; e < 32; ++e) {
            const float s = st[g * 32 + e];
            aq += s * Wq[e * 32 + d];
            ak += s * Wk[e * 32 + d];
            av += s * Wv[e * 32 + d];
            ac += s * Wcq[e * 32 + d];
        }
        qm[i] = aq; km[i] = ak; vm[i] = av; cqm[i] = ac;
    }
    const float* cbp = ctx + (long)bh * (NSC * NDC);
    for (int i = tid; i < 2048; i += 256) {
        const int s_ = i >> 5, d = i & 31;
        float w1 = bck[d], w2 = bcv[d];
        #pragma unroll
        for (int e = 0; e < 32; ++e) {
            const float cval = cbp[s_ * 32 + e];
            w1 += cval * Wck[e * 32 + d];
            w2 += cval * Wcv[e * 32 + d];
        }
        ckm[i] = w1; cvm[i] = w2;
    }
    __syncthreads();

    const float scale = 0.17677669529663687f;
    for (int i = tid; i < 1024; i += 256) {
        const int g = i >> 5, m = i & 31;
        float a = 0.f;
        #pragma unroll
        for (int d = 0; d < 32; ++d) a += qm[g * 32 + d] * km[m * 32 + d];
        attn[i] = a * scale;
    }
    __syncthreads();
    if (tid < 32) {
        float mx = -1e30f;
        for (int m = 0; m < 32; ++m) mx = fmaxf(mx, attn[tid * 32 + m]);
        float s = 0.f;
        for (int m = 0; m < 32; ++m) { const float e = expf(attn[tid * 32 + m] - mx); attn[tid * 32 + m] = e; s += e; }
        const float inv = 1.f / s;
        for (int m = 0; m < 32; ++m) attn[tid * 32 + m] *= inv;
    }
    __syncthreads();
    for (int i = tid; i < 1024; i += 256) {
        const int g = i >> 5, d = i & 31;
        float a = 0.f;
        #pragma unroll
        for (int m = 0; m < 32; ++m) a += attn[g * 32 + m] * vm[m * 32 + d];
        stok[i] = a;
    }
    __syncthreads();
    for (int i = tid; i < 2048; i += 256) {
        const int g = i >> 6, s_ = i & 63;
        float a = 0.f;
        #pragma unroll
        for (int d = 0; d < 32; ++d) a += cqm[g * 32 + d] * ckm[s_ * 32 + d];
        attn[i] = a * scale;
    }
    __syncthreads();
    if (tid < 32) {
        float mx = -1e30f;
        for (int m = 0; m < 64; ++m) mx = fmaxf(mx, attn[tid * 64 + m]);
        float s = 0.f;
        for (int m = 0; m < 64; ++m) { const float e = expf(attn[tid * 64 + m] - mx); attn[tid * 64 + m] = e; s += e; }
        const float inv = 1.f / s;
        for (int m = 0; m < 64; ++m) attn[tid * 64 + m] *= inv;
    }
    __syncthreads();
    const float mw = 1.f / (1.f + expf(-mix[0]));
    for (int i = tid; i < 1024; i += 256) {
        const int g = i >> 5, d = i & 31;
        float a = 0.f;
        #pragma unroll
        for (int s_ = 0; s_ < 64; ++s_) a += attn[g * 64 + s_] * cvm[s_ * 32 + d];
        const float val = mw * stok[i] + (1.f - mw) * a;
        ostT_o[(long)bh * 1024 + d * 32 + g] = __float2bfloat16(val);
    }
}

// ---------------------------------------------------------------------------
// Kernel 45 (fused, 8 waves, 64KB LDS): de-slice + Wout GEMM + LN2 + MLP.
// r22 structure; Wout GEMM re-scoped (unroll 1, per-mt A-frags) to trim the
// residual ~36MB spill under the 64-arch-VGPR clamp.
// ---------------------------------------------------------------------------
__global__ __launch_bounds__(512, 4) void k45_fused(
    const __hip_bfloat16* __restrict__ sw, const __hip_bfloat16* __restrict__ ostT,
    const __hip_bfloat16* __restrict__ woutt, const float* __restrict__ bout,
    const float* __restrict__ fx,
    const float* __restrict__ g2, const float* __restrict__ b2,
    const __hip_bfloat16* __restrict__ w1t, const float* __restrict__ bm1,
    const __hip_bfloat16* __restrict__ w2t, const float* __restrict__ bm2,
    float* __restrict__ out)
{
    __shared__ __align__(16) char lds[65536];
    const int tid = threadIdx.x;
    const int lane = tid & 63, wid = tid >> 6;   // 8 waves
    const long tok0 = (long)blockIdx.x * 64;
    const int b = (int)(tok0 >> 15);
    const int col = lane & 15, kq = lane >> 4;
    const int swz = (col & 7) << 4;
    const int ep = ((kq * 16) ^ swz) & 48;
    const int e0 = (swz & 64) | ep;
    const int e1 = ((swz & 64) ^ 64) | ep;
    const int ab0 = col * 512 + e0, ab1 = col * 512 + e1;
    const int cb0 = col * 256 + e0, cb1 = col * 256 + e1;

    // ---- stage sw -> [0,32K) bf16 swizzled ----
    #pragma unroll
    for (int it = 0; it < 4; ++it) {
        const int idx = it * 512 + tid;
        const int row = idx >> 5, ch = idx & 31;
        const short8v val = *reinterpret_cast<const short8v*>(
            reinterpret_cast<const short*>(sw) + (tok0 + row) * 256 + ch * 8);
        *reinterpret_cast<short8v*>(lds + row * 512 + ((ch * 16) ^ ((row & 7) << 4))) = val;
    }
    __syncthreads();

    // ---- de-slice via MFMA: wave handles head h = wid ----
    {
        f32x4 accal[4][2];
        const int abh = col * 512 + (((wid * 64) | (kq * 16)) ^ swz);
        short8v a[4];
        #pragma unroll
        for (int mt = 0; mt < 4; ++mt)
            a[mt] = *reinterpret_cast<const short8v*>(lds + mt * 8192 + abh);
        #pragma unroll
        for (int nt = 0; nt < 2; ++nt) {
            const int d = nt * 16 + col;
            const short8v bfr = *reinterpret_cast<const short8v*>(
                reinterpret_cast<const short*>(ostT) + ((b * 8 + wid) * 32 + d) * 32 + kq * 8);
            #pragma unroll
            for (int mt = 0; mt < 4; ++mt) {
                accal[mt][nt] = (f32x4){0.f, 0.f, 0.f, 0.f};
                accal[mt][nt] = __builtin_amdgcn_mfma_f32_16x16x32_bf16(
                    a[mt], bfr, accal[mt][nt], 0, 0, 0);
            }
        }
        #pragma unroll
        for (int nt = 0; nt < 2; ++nt) {
            const int cc = wid * 32 + nt * 16 + col;
            #pragma unroll
            for (int mt = 0; mt < 4; ++mt) {
                #pragma unroll
                for (int r = 0; r < 4; ++r) {
                    const int row = mt * 16 + kq * 4 + r;
                    const int byte = 32768 + row * 512 + ((cc * 2) ^ ((row & 7) << 4));
                    *reinterpret_cast<short*>(lds + byte) = f2bf(accal[mt][nt][r]);
                }
            }
        }
    }
    __syncthreads();

    // ---- Wout GEMM (unroll 1, per-mt scoped A-frags: low live-range) ----
    f32x4 acc[4][2];
    #pragma unroll
    for (int mt = 0; mt < 4; ++mt)
        #pragma unroll
        for (int nt = 0; nt < 2; ++nt) acc[mt][nt] = (f32x4){0.f, 0.f, 0.f, 0.f};

    {
        const short* wp = reinterpret_cast<const short*>(woutt) + (wid * 32 + col) * 256 + kq * 8;
        #pragma unroll 1
        for (int j = 0; j < 4; ++j) {
            short8v b0[2], b1[2];
            #pragma unroll
            for (int nt = 0; nt < 2; ++nt) {
                b0[nt] = *reinterpret_cast<const short8v*>(wp + nt * 4096 + j * 64);
                b1[nt] = *reinterpret_cast<const short8v*>(wp + nt * 4096 + j * 64 + 32);
            }
            #pragma unroll
            for (int mt = 0; mt < 4; ++mt) {
                const short8v x0 = *reinterpret_cast<const short8v*>(lds + 32768 + mt * 8192 + j * 128 + ab0);
                const short8v x1 = *reinterpret_cast<const short8v*>(lds + 32768 + mt * 8192 + j * 128 + ab1);
                #pragma unroll
                for (int nt = 0; nt < 2; ++nt) {
                    acc[mt][nt] = __builtin_amdgcn_mfma_f32_16x16x32_bf16(x0, b0[nt], acc[mt][nt], 0, 0, 0);
                    acc[mt][nt] = __builtin_amdgcn_mfma_f32_16x16x32_bf16(x1, b1[nt], acc[mt][nt], 0, 0, 0);
                }
            }
        }
    }

    // ---- stage attn output (acc+bout) as f32 [64][256] ----
    __syncthreads();
    float* lf = reinterpret_cast<float*>(lds);
    #pragma unroll
    for (int nt = 0; nt < 2; ++nt) {
        const int c = wid * 32 + nt * 16 + col;
        const float bb = bout[c];
        #pragma unroll
        for (int mt = 0; mt < 4; ++mt) {
            #pragma unroll
            for (int r = 0; r < 4; ++r) {
                const int row = mt * 16 + kq * 4 + r;
                lf[row * 256 + c] = acc[mt][nt][r] + bb;
            }
        }
    }
    __syncthreads();

    // ---- LN2: read attn tile + fx; store out_attn to global NOW ----
    short4v aout[8];
    {
        const float4 gv = *reinterpret_cast<const float4*>(g2 + lane * 4);
        const float4 bv = *reinterpret_cast<const float4*>(b2 + lane * 4);
        #pragma unroll
        for (int tt = 0; tt < 8; ++tt) {
            const int r = wid * 8 + tt;
            const float4 l4 = *reinterpret_cast<const float4*>(lf + r * 256 + lane * 4);
            const float4 f4 = *reinterpret_cast<const float4*>(fx + (tok0 + r) * 256 + lane * 4);
            float4 oa;
            oa.x = l4.x + f4.x; oa.y = l4.y + f4.y;
            oa.z = l4.z + f4.z; oa.w = l4.w + f4.w;
            *reinterpret_cast<float4*>(out + (tok0 + r) * 256 + lane * 4) = oa;
            float s = oa.x + oa.y + oa.z + oa.w;
            float s2 = oa.x * oa.x + oa.y * oa.y + oa.z * oa.z + oa.w * oa.w;
            #pragma unroll
            for (int off = 32; off; off >>= 1) {
                s  += __shfl_xor(s,  off);
                s2 += __shfl_xor(s2, off);
            }
            const float mean = s * (1.f / 256.f);
            const float rs = rsqrtf(s2 * (1.f / 256.f) - mean * mean + 1e-5f);
            aout[tt][0] = f2bf((oa.x - mean) * rs * gv.x + bv.x);
            aout[tt][1] = f2bf((oa.y - mean) * rs * gv.y + bv.y);
            aout[tt][2] = f2bf((oa.z - mean) * rs * gv.z + bv.z);
            aout[tt][3] = f2bf((oa.w - mean) * rs * gv.w + bv.w);
        }
    }
    __syncthreads();
    #pragma unroll
    for (int tt = 0; tt < 8; ++tt) {
        const int r = wid * 8 + tt;
        const int addr = r * 512 + ((lane * 8) ^ ((r & 7) << 4));
        *reinterpret_cast<short4v*>(lds + addr) = aout[tt];
    }
    __syncthreads();

    // ---- MLP: chunk=128, A2 double-buffered (16KB each), 1 barrier/chunk ----
    const int n0 = wid * 32;
    const int h0 = wid * 16;
    const short* w1s = reinterpret_cast<const short*>(w1t) + (h0 + col) * 256 + kq * 8;
    const short* w2s = reinterpret_cast<const short*>(w2t) + (n0 + col) * 1024 + kq * 8;

    f32x4 accO[4][2];
    #pragma unroll
    for (int mt = 0; mt < 4; ++mt)
        #pragma unroll
        for (int nt = 0; nt < 2; ++nt) accO[mt][nt] = (f32x4){0.f, 0.f, 0.f, 0.f};

    for (int ch = 0; ch < 8; ++ch) {
        const int abuf = 32768 + (ch & 1) * 16384;

        f32x4 accP[4];
        #pragma unroll
        for (int mt = 0; mt < 4; ++mt) accP[mt] = (f32x4){0.f, 0.f, 0.f, 0.f};

        #pragma unroll 1
        for (int j = 0; j < 4; ++j) {
            const short8v b0 = *reinterpret_cast<const short8v*>(w1s + ch * 32768 + j * 64);
            const short8v b1 = *reinterpret_cast<const short8v*>(w1s + ch * 32768 + j * 64 + 32);
            #pragma unroll
            for (int mt = 0; mt < 4; ++mt) {
                const short8v a0 = *reinterpret_cast<const short8v*>(lds + mt * 8192 + j * 128 + ab0);
                const short8v a1 = *reinterpret_cast<const short8v*>(lds + mt * 8192 + j * 128 + ab1);
                accP[mt] = __builtin_amdgcn_mfma_f32_16x16x32_bf16(a0, b0, accP[mt], 0, 0, 0);
                accP[mt] = __builtin_amdgcn_mfma_f32_16x16x32_bf16(a1, b1, accP[mt], 0, 0, 0);
            }
        }

        {
            const float b1v = bm1[ch * 128 + h0 + col];
            const int k2i2 = (h0 + col) * 2;
            #pragma unroll
            for (int mt = 0; mt < 4; ++mt) {
                #pragma unroll
                for (int r = 0; r < 4; ++r) {
                    float m = accP[mt][r] + b1v;
                    const float u = __builtin_fmaf(0.044715f * m, m * m, m);
                    const float e = __expf(-1.5957691216057308f * u);
                    m = m * __builtin_amdgcn_rcpf(1.f + e);
                    const int row = mt * 16 + kq * 4 + r;
                    const int byte = abuf + row * 256 + (k2i2 ^ ((row & 7) << 4));
                    *reinterpret_cast<short*>(lds + byte) = f2bf(m);
                }
            }
        }
        __syncthreads();

        #pragma unroll 1
        for (int j = 0; j < 2; ++j) {
            short8v b20[2], b21[2];
            #pragma unroll
            for (int nt = 0; nt < 2; ++nt) {
                b20[nt] = *reinterpret_cast<const short8v*>(w2s + nt * 16384 + ch * 128 + j * 64);
                b21[nt] = *reinterpret_cast<const short8v*>(w2s + nt * 16384 + ch * 128 + j * 64 + 32);
            }
            #pragma unroll
            for (int mt = 0; mt < 4; ++mt) {
                const short8v x0 = *reinterpret_cast<const short8v*>(lds + abuf + mt * 4096 + j * 128 + cb0);
                const short8v x1 = *reinterpret_cast<const short8v*>(lds + abuf + mt * 4096 + j * 128 + cb1);
                #pragma unroll
                for (int nt = 0; nt < 2; ++nt) {
                    accO[mt][nt] = __builtin_amdgcn_mfma_f32_16x16x32_bf16(x0, b20[nt], accO[mt][nt], 0, 0, 0);
                    accO[mt][nt] = __builtin_amdgcn_mfma_f32_16x16x32_bf16(x1, b21[nt], accO[mt][nt], 0, 0, 0);
                }
            }
        }
    }

    // ---- epilogue: accO+bm2 -> lf; out += mlp (RMW) ----
    __syncthreads();
    #pragma unroll
    for (int nt = 0; nt < 2; ++nt) {
        const int c = n0 + nt * 16 + col;
        const float b2v = bm2[c];
        #pragma unroll
        for (int mt = 0; mt < 4; ++mt) {
            #pragma unroll
            for (int r = 0; r < 4; ++r) {
                const int row = mt * 16 + kq * 4 + r;
                lf[row * 256 + c] = accO[mt][nt][r] + b2v;
            }
        }
    }
    __syncthreads();
    #pragma unroll
    for (int tt = 0; tt < 8; ++tt) {
        const int r = wid * 8 + tt;
        const float4 m4 = *reinterpret_cast<const float4*>(lf + r * 256 + lane * 4);
        const long gidx = (tok0 + r) * 256 + lane * 4;
        const float4 oa = *reinterpret_cast<const float4*>(out + gidx);
        float4 o;
        o.x = oa.x + m4.x; o.y = oa.y + m4.y;
        o.z = oa.z + m4.z; o.w = oa.w + m4.w;
        *reinterpret_cast<float4*>(out + gidx) = o;
    }
}

// ---------------------------------------------------------------------------
extern "C" void kernel_launch(void* const* d_in, const int* in_sizes, int n_in,
                              void* d_out, int out_size, void* d_ws, size_t ws_size,
                              hipStream_t stream)
{
    const float* fx   = (const float*)d_in[0];
    const float* ctx  = (const float*)d_in[1];
    const float* g1   = (const float*)d_in[2];
    const float* b1   = (const float*)d_in[3];
    const float* Wfx  = (const float*)d_in[4];
    const float* bfx  = (const float*)d_in[5];
    const float* Wx   = (const float*)d_in[6];
    const float* bx   = (const float*)d_in[7];
    const float* Wsl  = (const float*)d_in[8];
    const float* bsl  = (const float*)d_in[9];
    const float* temp = (const float*)d_in[10];
    const float* Wq   = (const float*)d_in[11];
    const float* Wk   = (const float*)d_in[12];
    const float* Wv   = (const float*)d_in[13];
    const float* Wcq  = (const float*)d_in[14];
    const float* bcq  = (const float*)d_in[15];
    const float* Wck  = (const float*)d_in[16];
    const float* bck  = (const float*)d_in[17];
    const float* Wcv  = (const float*)d_in[18];
    const float* bcv  = (const float*)d_in[19];
    const float* mix  = (const float*)d_in[20];
    const float* Wout = (const float*)d_in[21];
    const float* bout = (const float*)d_in[22];
    const float* g2   = (const float*)d_in[23];
    const float* b2   = (const float*)d_in[24];
    const float* Wm1  = (const float*)d_in[25];
    const float* bm1  = (const float*)d_in[26];
    const float* Wm2  = (const float*)d_in[27];
    const float* bm2  = (const float*)d_in[28];
    float* out = (float*)d_out;

    char* ws = (char*)d_ws;
    __hip_bfloat16* fxm  = (__hip_bfloat16*)ws;                         // 32MB
    __hip_bfloat16* sw   = (__hip_bfloat16*)(ws + (size_t)33554432);    // 32MB
    float* pst = (float*)(ws + (size_t)67108864);                       // 2MB
    float* pn  = (float*)(ws + (size_t)69206016);                       // 64KB
    __hip_bfloat16* ostT  = (__hip_bfloat16*)(ws + (size_t)69271552);   // 32KB
    __hip_bfloat16* wcat  = (__hip_bfloat16*)(ws + (size_t)69304320);   // 256KB [Wfx^T; Wcomb^T]
    __hip_bfloat16* woutt = (__hip_bfloat16*)(ws + (size_t)69566464);   // 128KB
    __hip_bfloat16* w1t   = (__hip_bfloat16*)(ws + (size_t)69697536);   // 512KB
    __hip_bfloat16* w2t   = (__hip_bfloat16*)(ws + (size_t)70221824);   // 512KB
    float* bcomb          = (float*)(ws + (size_t)70746112);            // 1KB

    kprep<<<896, 256, 0, stream>>>(Wfx, wcat, Wout, woutt, Wm1, w1t, Wm2, w2t,
                                   Wx, bx, Wsl, bsl, bcomb);

    k1_mfma<<<1024, 512, 0, stream>>>(fx, g1, b1, wcat, bfx, bcomb, temp,
                                      fxm, sw);
    k2_st_partial<<<512, 512, 0, stream>>>(fxm, sw, pst, pn);
    k3_slice_attn<<<16, 256, 0, stream>>>(pst, pn, ctx, Wq, Wk, Wv,
                                          Wcq, bcq, Wck, bck, Wcv, bcv, mix, ostT);
    k45_fused<<<1024, 512, 0, stream>>>(sw, ostT, woutt, bout, fx,
                                        g2, b2, w1t, bm1, w2t, bm2, out);
}

// Round 26
// 294.786 us; speedup vs baseline: 1.1240x; 1.0436x over previous
//
#include <hip/hip_runtime.h>
#include <hip/hip_bf16.h>

#define BATCH 2
#define NTOK  32768
#define CH    256
#define NH    8
#define HDIM  32
#define NG    32
#define NSC   64
#define NDC   32

typedef __attribute__((ext_vector_type(8))) short short8v;
typedef __attribute__((ext_vector_type(4))) short short4v;
typedef __attribute__((ext_vector_type(4))) float f32x4;

static __device__ __forceinline__ short f2bf(float f) {
    __hip_bfloat16 h = __float2bfloat16(f);
    return __builtin_bit_cast(short, h);
}
static __device__ __forceinline__ float bf2f(short s) {
    return __bfloat162float(__builtin_bit_cast(__hip_bfloat16, s));
}

// ---------------------------------------------------------------------------
// Prep kernel: 4 weight transposes (blocks 0-639) + kcomb (blocks 640-895).
// ---------------------------------------------------------------------------
static __device__ __forceinline__ void transpose_tile(
    const float* __restrict__ in, __hip_bfloat16* __restrict__ out,
    int K, int N, int blk, int tid)
{
    __shared__ float t[32][33];
    const int nb = N >> 5;
    const int bk = blk / nb;
    const int bn = blk % nb;
    const int c = tid & 31, r0 = tid >> 5;
    #pragma unroll
    for (int i = 0; i < 4; ++i) {
        const int r = r0 + i * 8;
        t[r][c] = in[(long)(bk * 32 + r) * N + bn * 32 + c];
    }
    __syncthreads();
    #pragma unroll
    for (int i = 0; i < 4; ++i) {
        const int r = r0 + i * 8;
        out[(long)(bn * 32 + r) * K + bk * 32 + c] = __float2bfloat16(t[c][r]);
    }
}

__global__ __launch_bounds__(256) void kprep(
    const float* __restrict__ Wfx, __hip_bfloat16* __restrict__ wcat,
    const float* __restrict__ Wout, __hip_bfloat16* __restrict__ woutt,
    const float* __restrict__ Wm1, __hip_bfloat16* __restrict__ w1t,
    const float* __restrict__ Wm2, __hip_bfloat16* __restrict__ w2t,
    const float* __restrict__ Wx, const float* __restrict__ bx,
    const float* __restrict__ Wsl, const float* __restrict__ bsl,
    float* __restrict__ bcomb)
{
    const int b = blockIdx.x, tid = threadIdx.x;
    if (b < 64)       { transpose_tile(Wfx,  wcat,  256, 256,  b,       tid); return; }
    else if (b < 128) { transpose_tile(Wout, woutt, 256, 256,  b - 64,  tid); return; }
    else if (b < 384) { transpose_tile(Wm1,  w1t,   256, 1024, b - 128, tid); return; }
    else if (b < 640) { transpose_tile(Wm2,  w2t,   1024, 256, b - 384, tid); return; }
    __shared__ float wcol[32];
    const int hc = b - 640;
    const int h = hc >> 5, g = hc & 31;
    if (tid < 32) wcol[tid] = Wsl[tid * 32 + g];
    __syncthreads();
    float a = 0.f;
    #pragma unroll
    for (int d = 0; d < 32; ++d) a += Wx[tid * 256 + h * 32 + d] * wcol[d];
    (wcat + 65536)[(long)hc * 256 + tid] = __float2bfloat16(a);
    if (tid == 0) {
        float s = bsl[g];
        #pragma unroll
        for (int d = 0; d < 32; ++d) s += bx[h * 32 + d] * wcol[d];
        bcomb[hc] = s;
    }
}

// ---------------------------------------------------------------------------
// Kernel 1 (MFMA, 8 waves / 512 thr): LN1 + GEMM + slice softmax + FUSED
// st-partials. At the end of the original k1, LDS holds [64][512] bf16:
// cols 0-255 = fxm, cols 256-511 = post-softmax sw — exactly what k2 re-read
// from HBM. The fused tail computes per-block psum[h][32][32] (wave = head,
// broadcast LDS reads) and writes partials; fxm is never materialized.
// ---------------------------------------------------------------------------
__global__ __launch_bounds__(512, 4) void k1_mfma(
    const float* __restrict__ fx,
    const float* __restrict__ g1, const float* __restrict__ b1,
    const __hip_bfloat16* __restrict__ wcat,   // [512][256]
    const float* __restrict__ bfx, const float* __restrict__ bcomb,
    const float* __restrict__ temp,
    float* __restrict__ psum_o, float* __restrict__ pn_o,
    __hip_bfloat16* __restrict__ sw_o)
{
    __shared__ __align__(16) char lds[65536];
    const int tid = threadIdx.x;
    const int lane = tid & 63, wid = tid >> 6;   // 8 waves
    const long tok0 = (long)blockIdx.x * 64;
    const int col = lane & 15, kq = lane >> 4;
    const int swz = (col & 7) << 4;
    const int ep = ((kq * 16) ^ swz) & 48;
    const int e0 = (swz & 64) | ep;
    const int e1 = ((swz & 64) ^ 64) | ep;
    const int ab0 = col * 512 + e0, ab1 = col * 512 + e1;

    {
        const float4 gv = *reinterpret_cast<const float4*>(g1 + lane * 4);
        const float4 bv = *reinterpret_cast<const float4*>(b1 + lane * 4);
        #pragma unroll
        for (int tt = 0; tt < 8; ++tt) {
            const int r = wid * 8 + tt;
            const float4 v = *reinterpret_cast<const float4*>(fx + (tok0 + r) * 256 + lane * 4);
            float s = v.x + v.y + v.z + v.w;
            float s2 = v.x * v.x + v.y * v.y + v.z * v.z + v.w * v.w;
            #pragma unroll
            for (int off = 32; off; off >>= 1) {
                s  += __shfl_xor(s,  off);
                s2 += __shfl_xor(s2, off);
            }
            const float mean = s * (1.f / 256.f);
            const float rs = rsqrtf(s2 * (1.f / 256.f) - mean * mean + 1e-5f);
            short4v o;
            o[0] = f2bf((v.x - mean) * rs * gv.x + bv.x);
            o[1] = f2bf((v.y - mean) * rs * gv.y + bv.y);
            o[2] = f2bf((v.z - mean) * rs * gv.z + bv.z);
            o[3] = f2bf((v.w - mean) * rs * gv.w + bv.w);
            const int addr = r * 512 + ((lane * 8) ^ ((r & 7) << 4));
            *reinterpret_cast<short4v*>(lds + addr) = o;
        }
    }
    __syncthreads();

    const int n0 = wid * 64;
    f32x4 acc[4][4];
    #pragma unroll
    for (int mt = 0; mt < 4; ++mt)
        #pragma unroll
        for (int nt = 0; nt < 4; ++nt) acc[mt][nt] = (f32x4){0.f, 0.f, 0.f, 0.f};

    const short* wp = reinterpret_cast<const short*>(wcat) + (n0 + col) * 256 + kq * 8;
    #pragma unroll 2
    for (int j = 0; j < 4; ++j) {
        short8v a0[4], a1[4];
        #pragma unroll
        for (int mt = 0; mt < 4; ++mt) {
            a0[mt] = *reinterpret_cast<const short8v*>(lds + mt * 8192 + j * 128 + ab0);
            a1[mt] = *reinterpret_cast<const short8v*>(lds + mt * 8192 + j * 128 + ab1);
        }
        #pragma unroll
        for (int nt = 0; nt < 4; ++nt) {
            const short8v b0 = *reinterpret_cast<const short8v*>(wp + nt * 4096 + j * 64);
            const short8v b1 = *reinterpret_cast<const short8v*>(wp + nt * 4096 + j * 64 + 32);
            #pragma unroll
            for (int mt = 0; mt < 4; ++mt) {
                acc[mt][nt] = __builtin_amdgcn_mfma_f32_16x16x32_bf16(a0[mt], b0, acc[mt][nt], 0, 0, 0);
                acc[mt][nt] = __builtin_amdgcn_mfma_f32_16x16x32_bf16(a1[mt], b1, acc[mt][nt], 0, 0, 0);
            }
        }
    }
    __syncthreads();

    #pragma unroll
    for (int nt = 0; nt < 4; ++nt) {
        const int c = n0 + nt * 16 + col;
        const float bb = (c < 256) ? bfx[c] : bcomb[c - 256];
        #pragma unroll
        for (int mt = 0; mt < 4; ++mt) {
            #pragma unroll
            for (int r = 0; r < 4; ++r) {
                const int row = mt * 16 + kq * 4 + r;
                const int byte = row * 1024 + ((c * 2) ^ ((row & 7) << 4));
                *reinterpret_cast<short*>(lds + byte) = f2bf(acc[mt][nt][r] + bb);
            }
        }
    }
    __syncthreads();

    // ---- slice softmax on logits (cols 256-511), in place ----
    {
        const int t = tid >> 3, h = tid & 7;
        const float it_ = 1.f / temp[h];
        float lg[32];
        #pragma unroll
        for (int g = 0; g < 32; ++g) {
            const int byte = t * 1024 + (((256 + h * 32 + g) * 2) ^ ((t & 7) << 4));
            lg[g] = bf2f(*reinterpret_cast<const short*>(lds + byte)) * it_;
        }
        float mx = -1e30f;
        #pragma unroll
        for (int g = 0; g < 32; ++g) mx = fmaxf(mx, lg[g]);
        float ssum = 0.f;
        #pragma unroll
        for (int g = 0; g < 32; ++g) { lg[g] = __expf(lg[g] - mx); ssum += lg[g]; }
        const float inv = 1.f / ssum;
        #pragma unroll
        for (int g = 0; g < 32; ++g) {
            const int byte = t * 1024 + (((256 + h * 32 + g) * 2) ^ ((t & 7) << 4));
            *reinterpret_cast<short*>(lds + byte) = f2bf(lg[g] * inv);
        }
    }
    __syncthreads();

    // ---- coalesced sw store (cols 256-511) ----
    #pragma unroll
    for (int it = 0; it < 4; ++it) {
        const int idx = it * 512 + tid;
        const int row = idx >> 5, ch = idx & 31;
        const short8v val = *reinterpret_cast<const short8v*>(
            lds + row * 1024 + ((512 + ch * 16) ^ ((row & 7) << 4)));
        *reinterpret_cast<short8v*>(
            reinterpret_cast<short*>(sw_o) + (tok0 + row) * 256 + ch * 8) = val;
    }

    // ---- FUSED st partials: wave = head, lane = (gB,dB); broadcast reads ----
    {
        const int h = wid;
        const int gB = lane >> 3, dB = lane & 7;
        const int csw = (256 + h * 32 + gB * 4) * 2;   // 8B-aligned
        const int cfx = (h * 32 + dB * 4) * 2;         // 8B-aligned
        float pac[4][4];
        float nacc[4];
        #pragma unroll
        for (int i = 0; i < 4; ++i) {
            nacc[i] = 0.f;
            #pragma unroll
            for (int j = 0; j < 4; ++j) pac[i][j] = 0.f;
        }
        #pragma unroll 4
        for (int t = 0; t < 64; ++t) {
            const int sb = t * 1024;
            const int sx = (t & 7) << 4;
            const short4v s4 = *reinterpret_cast<const short4v*>(lds + sb + (csw ^ sx));
            const short4v f4 = *reinterpret_cast<const short4v*>(lds + sb + (cfx ^ sx));
            float sg[4], fd[4];
            #pragma unroll
            for (int i = 0; i < 4; ++i) { sg[i] = bf2f(s4[i]); fd[i] = bf2f(f4[i]); }
            #pragma unroll
            for (int gg = 0; gg < 4; ++gg) {
                nacc[gg] += sg[gg];
                #pragma unroll
                for (int dd = 0; dd < 4; ++dd) pac[gg][dd] += sg[gg] * fd[dd];
            }
        }
        float* pg = psum_o + (long)blockIdx.x * 8192 + h * 1024;
        #pragma unroll
        for (int gg = 0; gg < 4; ++gg) {
            f32x4 v;
            v[0] = pac[gg][0]; v[1] = pac[gg][1];
            v[2] = pac[gg][2]; v[3] = pac[gg][3];
            *reinterpret_cast<f32x4*>(pg + (gB * 4 + gg) * 32 + dB * 4) = v;
        }
        if (dB == 0) {
            #pragma unroll
            for (int gg = 0; gg < 4; ++gg)
                pn_o[blockIdx.x * 256 + h * 32 + gB * 4 + gg] = nacc[gg];
        }
    }
}

// ---------------------------------------------------------------------------
// Kernel 2' : reduce 16 per-k1-block partials -> pst/pn (layout identical to
// the old k2 output, so k3 is unchanged).
// ---------------------------------------------------------------------------
__global__ __launch_bounds__(256) void k2_reduce(
    const float* __restrict__ psum_g, const float* __restrict__ pn_g,
    float* __restrict__ pst, float* __restrict__ pn)
{
    const int blk = blockIdx.x;          // [0,512): row index consumed by k3
    const int bh = blk >> 5, c = blk & 31;
    const int b = bh >> 3, h = bh & 7;
    const int i0 = b * 512 + c * 16;     // first source k1-block
    const int tid = threadIdx.x;
    const int e4 = tid * 4;              // 256 thr x 4 floats = 1024
    f32x4 s = (f32x4){0.f, 0.f, 0.f, 0.f};
    #pragma unroll 4
    for (int j = 0; j < 16; ++j) {
        const f32x4 v = *reinterpret_cast<const f32x4*>(
            psum_g + ((long)(i0 + j) * 8 + h) * 1024 + e4);
        s[0] += v[0]; s[1] += v[1]; s[2] += v[2]; s[3] += v[3];
    }
    *reinterpret_cast<f32x4*>(pst + (long)blk * 1024 + e4) = s;
    if (tid < 32) {
        float t = 0.f;
        #pragma unroll
        for (int j = 0; j < 16; ++j)
            t += pn_g[(i0 + j) * 256 + h * 32 + tid];
        pn[blk * 32 + tid] = t;
    }
}

// ---------------------------------------------------------------------------
// Kernel 3: reduce partials -> st; slice self-attn + cross-attn -> ostT (bf16).
// ---------------------------------------------------------------------------
__global__ __launch_bounds__(256) void k3_slice_attn(
    const float* __restrict__ pst, const float* __restrict__ pn,
    const float* __restrict__ ctx,
    const float* __restrict__ Wq, const float* __restrict__ Wk, const float* __restrict__ Wv,
    const float* __restrict__ Wcq, const float* __restrict__ bcq,
    const float* __restrict__ Wck, const float* __restrict__ bck,
    const float* __restrict__ Wcv, const float* __restrict__ bcv,
    const float* __restrict__ mix, __hip_bfloat16* __restrict__ ostT_o)
{
    __shared__ float st[1024], qm[1024], km[1024], vm[1024], cqm[1024];
    __shared__ float ckm[2048], cvm[2048], attn[2048], stok[1024], nb[32];
    const int tid = threadIdx.x;
    const int bh = blockIdx.x;

    if (tid < 32) {
        float s = 0.f;
        for (int c = 0; c < 32; ++c) s += pn[(bh * 32 + c) * 32 + tid];
        nb[tid] = s;
    }
    __syncthreads();
    for (int i = tid; i < 1024; i += 256) {
        float s = 0.f;
        for (int c = 0; c < 32; ++c) s += pst[(long)(bh * 32 + c) * 1024 + i];
        st[i] = s / (nb[i >> 5] + 1e-5f);
    }
    __syncthreads();

    for (int i = tid; i < 1024; i += 256) {
        const int g = i >> 5, d = i & 31;
        float aq = 0.f, ak = 0.f, av = 0.f, ac = bcq[d];
        #pragma unroll
        for (int e = 0; e < 32; ++e) {
            const float s = st[g * 32 + e];
            aq += s * Wq[e * 32 + d];
            ak += s * Wk[e * 32 + d];
            av += s * Wv[e * 32 + d];
            ac += s * Wcq[e * 32 + d];
        }
        qm[i] = aq; km[i] = ak; vm[i] = av; cqm[i] = ac;
    }
    const float* cbp = ctx + (long)bh * (NSC * NDC);
    for (int i = tid; i < 2048; i += 256) {
        const int s_ = i >> 5, d = i & 31;
        float w1 = bck[d], w2 = bcv[d];
        #pragma unroll
        for (int e = 0; e < 32; ++e) {
            const float cval = cbp[s_ * 32 + e];
            w1 += cval * Wck[e * 32 + d];
            w2 += cval * Wcv[e * 32 + d];
        }
        ckm[i] = w1; cvm[i] = w2;
    }
    __syncthreads();

    const float scale = 0.17677669529663687f;
    for (int i = tid; i < 1024; i += 256) {
        const int g = i >> 5, m = i & 31;
        float a = 0.f;
        #pragma unroll
        for (int d = 0; d < 32; ++d) a += qm[g * 32 + d] * km[m * 32 + d];
        attn[i] = a * scale;
    }
    __syncthreads();
    if (tid < 32) {
        float mx = -1e30f;
        for (int m = 0; m < 32; ++m) mx = fmaxf(mx, attn[tid * 32 + m]);
        float s = 0.f;
        for (int m = 0; m < 32; ++m) { const float e = expf(attn[tid * 32 + m] - mx); attn[tid * 32 + m] = e; s += e; }
        const float inv = 1.f / s;
        for (int m = 0; m < 32; ++m) attn[tid * 32 + m] *= inv;
    }
    __syncthreads();
    for (int i = tid; i < 1024; i += 256) {
        const int g = i >> 5, d = i & 31;
        float a = 0.f;
        #pragma unroll
        for (int m = 0; m < 32; ++m) a += attn[g * 32 + m] * vm[m * 32 + d];
        stok[i] = a;
    }
    __syncthreads();
    for (int i = tid; i < 2048; i += 256) {
        const int g = i >> 6, s_ = i & 63;
        float a = 0.f;
        #pragma unroll
        for (int d = 0; d < 32; ++d) a += cqm[g * 32 + d] * ckm[s_ * 32 + d];
        attn[i] = a * scale;
    }
    __syncthreads();
    if (tid < 32) {
        float mx = -1e30f;
        for (int m = 0; m < 64; ++m) mx = fmaxf(mx, attn[tid * 64 + m]);
        float s = 0.f;
        for (int m = 0; m < 64; ++m) { const float e = expf(attn[tid * 64 + m] - mx); attn[tid * 64 + m] = e; s += e; }
        const float inv = 1.f / s;
        for (int m = 0; m < 64; ++m) attn[tid * 64 + m] *= inv;
    }
    __syncthreads();
    const float mw = 1.f / (1.f + expf(-mix[0]));
    for (int i = tid; i < 1024; i += 256) {
        const int g = i >> 5, d = i & 31;
        float a = 0.f;
        #pragma unroll
        for (int s_ = 0; s_ < 64; ++s_) a += attn[g * 64 + s_] * cvm[s_ * 32 + d];
        const float val = mw * stok[i] + (1.f - mw) * a;
        ostT_o[(long)bh * 1024 + d * 32 + g] = __float2bfloat16(val);
    }
}

// ---------------------------------------------------------------------------
// Kernel 45 (fused, 8 waves, 64KB LDS): de-slice + Wout GEMM + LN2 + MLP.
// r25-proven (unchanged).
// ---------------------------------------------------------------------------
__global__ __launch_bounds__(512, 4) void k45_fused(
    const __hip_bfloat16* __restrict__ sw, const __hip_bfloat16* __restrict__ ostT,
    const __hip_bfloat16* __restrict__ woutt, const float* __restrict__ bout,
    const float* __restrict__ fx,
    const float* __restrict__ g2, const float* __restrict__ b2,
    const __hip_bfloat16* __restrict__ w1t, const float* __restrict__ bm1,
    const __hip_bfloat16* __restrict__ w2t, const float* __restrict__ bm2,
    float* __restrict__ out)
{
    __shared__ __align__(16) char lds[65536];
    const int tid = threadIdx.x;
    const int lane = tid & 63, wid = tid >> 6;   // 8 waves
    const long tok0 = (long)blockIdx.x * 64;
    const int b = (int)(tok0 >> 15);
    const int col = lane & 15, kq = lane >> 4;
    const int swz = (col & 7) << 4;
    const int ep = ((kq * 16) ^ swz) & 48;
    const int e0 = (swz & 64) | ep;
    const int e1 = ((swz & 64) ^ 64) | ep;
    const int ab0 = col * 512 + e0, ab1 = col * 512 + e1;
    const int cb0 = col * 256 + e0, cb1 = col * 256 + e1;

    // ---- stage sw -> [0,32K) bf16 swizzled ----
    #pragma unroll
    for (int it = 0; it < 4; ++it) {
        const int idx = it * 512 + tid;
        const int row = idx >> 5, ch = idx & 31;
        const short8v val = *reinterpret_cast<const short8v*>(
            reinterpret_cast<const short*>(sw) + (tok0 + row) * 256 + ch * 8);
        *reinterpret_cast<short8v*>(lds + row * 512 + ((ch * 16) ^ ((row & 7) << 4))) = val;
    }
    __syncthreads();

    // ---- de-slice via MFMA: wave handles head h = wid ----
    {
        f32x4 accal[4][2];
        const int abh = col * 512 + (((wid * 64) | (kq * 16)) ^ swz);
        short8v a[4];
        #pragma unroll
        for (int mt = 0; mt < 4; ++mt)
            a[mt] = *reinterpret_cast<const short8v*>(lds + mt * 8192 + abh);
        #pragma unroll
        for (int nt = 0; nt < 2; ++nt) {
            const int d = nt * 16 + col;
            const short8v bfr = *reinterpret_cast<const short8v*>(
                reinterpret_cast<const short*>(ostT) + ((b * 8 + wid) * 32 + d) * 32 + kq * 8);
            #pragma unroll
            for (int mt = 0; mt < 4; ++mt) {
                accal[mt][nt] = (f32x4){0.f, 0.f, 0.f, 0.f};
                accal[mt][nt] = __builtin_amdgcn_mfma_f32_16x16x32_bf16(
                    a[mt], bfr, accal[mt][nt], 0, 0, 0);
            }
        }
        #pragma unroll
        for (int nt = 0; nt < 2; ++nt) {
            const int cc = wid * 32 + nt * 16 + col;
            #pragma unroll
            for (int mt = 0; mt < 4; ++mt) {
                #pragma unroll
                for (int r = 0; r < 4; ++r) {
                    const int row = mt * 16 + kq * 4 + r;
                    const int byte = 32768 + row * 512 + ((cc * 2) ^ ((row & 7) << 4));
                    *reinterpret_cast<short*>(lds + byte) = f2bf(accal[mt][nt][r]);
                }
            }
        }
    }
    __syncthreads();

    // ---- Wout GEMM (unroll 1, per-mt scoped A-frags: low live-range) ----
    f32x4 acc[4][2];
    #pragma unroll
    for (int mt = 0; mt < 4; ++mt)
        #pragma unroll
        for (int nt = 0; nt < 2; ++nt) acc[mt][nt] = (f32x4){0.f, 0.f, 0.f, 0.f};

    {
        const short* wp = reinterpret_cast<const short*>(woutt) + (wid * 32 + col) * 256 + kq * 8;
        #pragma unroll 1
        for (int j = 0; j < 4; ++j) {
            short8v b0[2], b1[2];
            #pragma unroll
            for (int nt = 0; nt < 2; ++nt) {
                b0[nt] = *reinterpret_cast<const short8v*>(wp + nt * 4096 + j * 64);
                b1[nt] = *reinterpret_cast<const short8v*>(wp + nt * 4096 + j * 64 + 32);
            }
            #pragma unroll
            for (int mt = 0; mt < 4; ++mt) {
                const short8v x0 = *reinterpret_cast<const short8v*>(lds + 32768 + mt * 8192 + j * 128 + ab0);
                const short8v x1 = *reinterpret_cast<const short8v*>(lds + 32768 + mt * 8192 + j * 128 + ab1);
                #pragma unroll
                for (int nt = 0; nt < 2; ++nt) {
                    acc[mt][nt] = __builtin_amdgcn_mfma_f32_16x16x32_bf16(x0, b0[nt], acc[mt][nt], 0, 0, 0);
                    acc[mt][nt] = __builtin_amdgcn_mfma_f32_16x16x32_bf16(x1, b1[nt], acc[mt][nt], 0, 0, 0);
                }
            }
        }
    }

    // ---- stage attn output (acc+bout) as f32 [64][256] ----
    __syncthreads();
    float* lf = reinterpret_cast<float*>(lds);
    #pragma unroll
    for (int nt = 0; nt < 2; ++nt) {
        const int c = wid * 32 + nt * 16 + col;
        const float bb = bout[c];
        #pragma unroll
        for (int mt = 0; mt < 4; ++mt) {
            #pragma unroll
            for (int r = 0; r < 4; ++r) {
                const int row = mt * 16 + kq * 4 + r;
                lf[row * 256 + c] = acc[mt][nt][r] + bb;
            }
        }
    }
    __syncthreads();

    // ---- LN2: read attn tile + fx; store out_attn to global NOW ----
    short4v aout[8];
    {
        const float4 gv = *reinterpret_cast<const float4*>(g2 + lane * 4);
        const float4 bv = *reinterpret_cast<const float4*>(b2 + lane * 4);
        #pragma unroll
        for (int tt = 0; tt < 8; ++tt) {
            const int r = wid * 8 + tt;
            const float4 l4 = *reinterpret_cast<const float4*>(lf + r * 256 + lane * 4);
            const float4 f4 = *reinterpret_cast<const float4*>(fx + (tok0 + r) * 256 + lane * 4);
            float4 oa;
            oa.x = l4.x + f4.x; oa.y = l4.y + f4.y;
            oa.z = l4.z + f4.z; oa.w = l4.w + f4.w;
            *reinterpret_cast<float4*>(out + (tok0 + r) * 256 + lane * 4) = oa;
            float s = oa.x + oa.y + oa.z + oa.w;
            float s2 = oa.x * oa.x + oa.y * oa.y + oa.z * oa.z + oa.w * oa.w;
            #pragma unroll
            for (int off = 32; off; off >>= 1) {
                s  += __shfl_xor(s,  off);
                s2 += __shfl_xor(s2, off);
            }
            const float mean = s * (1.f / 256.f);
            const float rs = rsqrtf(s2 * (1.f / 256.f) - mean * mean + 1e-5f);
            aout[tt][0] = f2bf((oa.x - mean) * rs * gv.x + bv.x);
            aout[tt][1] = f2bf((oa.y - mean) * rs * gv.y + bv.y);
            aout[tt][2] = f2bf((oa.z - mean) * rs * gv.z + bv.z);
            aout[tt][3] = f2bf((oa.w - mean) * rs * gv.w + bv.w);
        }
    }
    __syncthreads();
    #pragma unroll
    for (int tt = 0; tt < 8; ++tt) {
        const int r = wid * 8 + tt;
        const int addr = r * 512 + ((lane * 8) ^ ((r & 7) << 4));
        *reinterpret_cast<short4v*>(lds + addr) = aout[tt];
    }
    __syncthreads();

    // ---- MLP: chunk=128, A2 double-buffered (16KB each), 1 barrier/chunk ----
    const int n0 = wid * 32;
    const int h0 = wid * 16;
    const short* w1s = reinterpret_cast<const short*>(w1t) + (h0 + col) * 256 + kq * 8;
    const short* w2s = reinterpret_cast<const short*>(w2t) + (n0 + col) * 1024 + kq * 8;

    f32x4 accO[4][2];
    #pragma unroll
    for (int mt = 0; mt < 4; ++mt)
        #pragma unroll
        for (int nt = 0; nt < 2; ++nt) accO[mt][nt] = (f32x4){0.f, 0.f, 0.f, 0.f};

    for (int ch = 0; ch < 8; ++ch) {
        const int abuf = 32768 + (ch & 1) * 16384;

        f32x4 accP[4];
        #pragma unroll
        for (int mt = 0; mt < 4; ++mt) accP[mt] = (f32x4){0.f, 0.f, 0.f, 0.f};

        #pragma unroll 1
        for (int j = 0; j < 4; ++j) {
            const short8v b0 = *reinterpret_cast<const short8v*>(w1s + ch * 32768 + j * 64);
            const short8v b1 = *reinterpret_cast<const short8v*>(w1s + ch * 32768 + j * 64 + 32);
            #pragma unroll
            for (int mt = 0; mt < 4; ++mt) {
                const short8v a0 = *reinterpret_cast<const short8v*>(lds + mt * 8192 + j * 128 + ab0);
                const short8v a1 = *reinterpret_cast<const short8v*>(lds + mt * 8192 + j * 128 + ab1);
                accP[mt] = __builtin_amdgcn_mfma_f32_16x16x32_bf16(a0, b0, accP[mt], 0, 0, 0);
                accP[mt] = __builtin_amdgcn_mfma_f32_16x16x32_bf16(a1, b1, accP[mt], 0, 0, 0);
            }
        }

        {
            const float b1v = bm1[ch * 128 + h0 + col];
            const int k2i2 = (h0 + col) * 2;
            #pragma unroll
            for (int mt = 0; mt < 4; ++mt) {
                #pragma unroll
                for (int r = 0; r < 4; ++r) {
                    float m = accP[mt][r] + b1v;
                    const float u = __builtin_fmaf(0.044715f * m, m * m, m);
                    const float e = __expf(-1.5957691216057308f * u);
                    m = m * __builtin_amdgcn_rcpf(1.f + e);
                    const int row = mt * 16 + kq * 4 + r;
                    const int byte = abuf + row * 256 + (k2i2 ^ ((row & 7) << 4));
                    *reinterpret_cast<short*>(lds + byte) = f2bf(m);
                }
            }
        }
        __syncthreads();

        #pragma unroll 1
        for (int j = 0; j < 2; ++j) {
            short8v b20[2], b21[2];
            #pragma unroll
            for (int nt = 0; nt < 2; ++nt) {
                b20[nt] = *reinterpret_cast<const short8v*>(w2s + nt * 16384 + ch * 128 + j * 64);
                b21[nt] = *reinterpret_cast<const short8v*>(w2s + nt * 16384 + ch * 128 + j * 64 + 32);
            }
            #pragma unroll
            for (int mt = 0; mt < 4; ++mt) {
                const short8v x0 = *reinterpret_cast<const short8v*>(lds + abuf + mt * 4096 + j * 128 + cb0);
                const short8v x1 = *reinterpret_cast<const short8v*>(lds + abuf + mt * 4096 + j * 128 + cb1);
                #pragma unroll
                for (int nt = 0; nt < 2; ++nt) {
                    accO[mt][nt] = __builtin_amdgcn_mfma_f32_16x16x32_bf16(x0, b20[nt], accO[mt][nt], 0, 0, 0);
                    accO[mt][nt] = __builtin_amdgcn_mfma_f32_16x16x32_bf16(x1, b21[nt], accO[mt][nt], 0, 0, 0);
                }
            }
        }
    }

    // ---- epilogue: accO+bm2 -> lf; out += mlp (RMW) ----
    __syncthreads();
    #pragma unroll
    for (int nt = 0; nt < 2; ++nt) {
        const int c = n0 + nt * 16 + col;
        const float b2v = bm2[c];
        #pragma unroll
        for (int mt = 0; mt < 4; ++mt) {
            #pragma unroll
            for (int r = 0; r < 4; ++r) {
                const int row = mt * 16 + kq * 4 + r;
                lf[row * 256 + c] = accO[mt][nt][r] + b2v;
            }
        }
    }
    __syncthreads();
    #pragma unroll
    for (int tt = 0; tt < 8; ++tt) {
        const int r = wid * 8 + tt;
        const float4 m4 = *reinterpret_cast<const float4*>(lf + r * 256 + lane * 4);
        const long gidx = (tok0 + r) * 256 + lane * 4;
        const float4 oa = *reinterpret_cast<const float4*>(out + gidx);
        float4 o;
        o.x = oa.x + m4.x; o.y = oa.y + m4.y;
        o.z = oa.z + m4.z; o.w = oa.w + m4.w;
        *reinterpret_cast<float4*>(out + gidx) = o;
    }
}

// ---------------------------------------------------------------------------
extern "C" void kernel_launch(void* const* d_in, const int* in_sizes, int n_in,
                              void* d_out, int out_size, void* d_ws, size_t ws_size,
                              hipStream_t stream)
{
    const float* fx   = (const float*)d_in[0];
    const float* ctx  = (const float*)d_in[1];
    const float* g1   = (const float*)d_in[2];
    const float* b1   = (const float*)d_in[3];
    const float* Wfx  = (const float*)d_in[4];
    const float* bfx  = (const float*)d_in[5];
    const float* Wx   = (const float*)d_in[6];
    const float* bx   = (const float*)d_in[7];
    const float* Wsl  = (const float*)d_in[8];
    const float* bsl  = (const float*)d_in[9];
    const float* temp = (const float*)d_in[10];
    const float* Wq   = (const float*)d_in[11];
    const float* Wk   = (const float*)d_in[12];
    const float* Wv   = (const float*)d_in[13];
    const float* Wcq  = (const float*)d_in[14];
    const float* bcq  = (const float*)d_in[15];
    const float* Wck  = (const float*)d_in[16];
    const float* bck  = (const float*)d_in[17];
    const float* Wcv  = (const float*)d_in[18];
    const float* bcv  = (const float*)d_in[19];
    const float* mix  = (const float*)d_in[20];
    const float* Wout = (const float*)d_in[21];
    const float* bout = (const float*)d_in[22];
    const float* g2   = (const float*)d_in[23];
    const float* b2   = (const float*)d_in[24];
    const float* Wm1  = (const float*)d_in[25];
    const float* bm1  = (const float*)d_in[26];
    const float* Wm2  = (const float*)d_in[27];
    const float* bm2  = (const float*)d_in[28];
    float* out = (float*)d_out;

    char* ws = (char*)d_ws;
    float* psum_g = (float*)ws;                                         // 32MB (old fxm slot: 1024x8x32x32 f32)
    __hip_bfloat16* sw   = (__hip_bfloat16*)(ws + (size_t)33554432);    // 32MB
    float* pst = (float*)(ws + (size_t)67108864);                       // 2MB
    float* pn  = (float*)(ws + (size_t)69206016);                       // 64KB
    __hip_bfloat16* ostT  = (__hip_bfloat16*)(ws + (size_t)69271552);   // 32KB
    __hip_bfloat16* wcat  = (__hip_bfloat16*)(ws + (size_t)69304320);   // 256KB [Wfx^T; Wcomb^T]
    __hip_bfloat16* woutt = (__hip_bfloat16*)(ws + (size_t)69566464);   // 128KB
    __hip_bfloat16* w1t   = (__hip_bfloat16*)(ws + (size_t)69697536);   // 512KB
    __hip_bfloat16* w2t   = (__hip_bfloat16*)(ws + (size_t)70221824);   // 512KB
    float* bcomb          = (float*)(ws + (size_t)70746112);            // 1KB
    float* pn_g           = (float*)(ws + (size_t)70747136);            // 1MB (1024x8x32 f32)

    kprep<<<896, 256, 0, stream>>>(Wfx, wcat, Wout, woutt, Wm1, w1t, Wm2, w2t,
                                   Wx, bx, Wsl, bsl, bcomb);

    k1_mfma<<<1024, 512, 0, stream>>>(fx, g1, b1, wcat, bfx, bcomb, temp,
                                      psum_g, pn_g, sw);
    k2_reduce<<<512, 256, 0, stream>>>(psum_g, pn_g, pst, pn);
    k3_slice_attn<<<16, 256, 0, stream>>>(pst, pn, ctx, Wq, Wk, Wv,
                                          Wcq, bcq, Wck, bck, Wcv, bcv, mix, ostT);
    k45_fused<<<1024, 512, 0, stream>>>(sw, ostT, woutt, bout, fx,
                                        g2, b2, w1t, bm1, w2t, bm2, out);
}

// Round 27
// 288.569 us; speedup vs baseline: 1.1482x; 1.0215x over previous
//
#include <hip/hip_runtime.h>
#include <hip/hip_bf16.h>

#define BATCH 2
#define NTOK  32768
#define CH    256
#define NH    8
#define HDIM  32
#define NG    32
#define NSC   64
#define NDC   32

typedef __attribute__((ext_vector_type(8))) short short8v;
typedef __attribute__((ext_vector_type(4))) short short4v;
typedef __attribute__((ext_vector_type(4))) float f32x4;

static __device__ __forceinline__ short f2bf(float f) {
    __hip_bfloat16 h = __float2bfloat16(f);
    return __builtin_bit_cast(short, h);
}
static __device__ __forceinline__ float bf2f(short s) {
    return __bfloat162float(__builtin_bit_cast(__hip_bfloat16, s));
}

// ---------------------------------------------------------------------------
// Prep kernel: 4 weight transposes (blocks 0-639) + kcomb (blocks 640-895).
// ---------------------------------------------------------------------------
static __device__ __forceinline__ void transpose_tile(
    const float* __restrict__ in, __hip_bfloat16* __restrict__ out,
    int K, int N, int blk, int tid)
{
    __shared__ float t[32][33];
    const int nb = N >> 5;
    const int bk = blk / nb;
    const int bn = blk % nb;
    const int c = tid & 31, r0 = tid >> 5;
    #pragma unroll
    for (int i = 0; i < 4; ++i) {
        const int r = r0 + i * 8;
        t[r][c] = in[(long)(bk * 32 + r) * N + bn * 32 + c];
    }
    __syncthreads();
    #pragma unroll
    for (int i = 0; i < 4; ++i) {
        const int r = r0 + i * 8;
        out[(long)(bn * 32 + r) * K + bk * 32 + c] = __float2bfloat16(t[c][r]);
    }
}

__global__ __launch_bounds__(256) void kprep(
    const float* __restrict__ Wfx, __hip_bfloat16* __restrict__ wcat,
    const float* __restrict__ Wout, __hip_bfloat16* __restrict__ woutt,
    const float* __restrict__ Wm1, __hip_bfloat16* __restrict__ w1t,
    const float* __restrict__ Wm2, __hip_bfloat16* __restrict__ w2t,
    const float* __restrict__ Wx, const float* __restrict__ bx,
    const float* __restrict__ Wsl, const float* __restrict__ bsl,
    float* __restrict__ bcomb)
{
    const int b = blockIdx.x, tid = threadIdx.x;
    if (b < 64)       { transpose_tile(Wfx,  wcat,  256, 256,  b,       tid); return; }
    else if (b < 128) { transpose_tile(Wout, woutt, 256, 256,  b - 64,  tid); return; }
    else if (b < 384) { transpose_tile(Wm1,  w1t,   256, 1024, b - 128, tid); return; }
    else if (b < 640) { transpose_tile(Wm2,  w2t,   1024, 256, b - 384, tid); return; }
    __shared__ float wcol[32];
    const int hc = b - 640;
    const int h = hc >> 5, g = hc & 31;
    if (tid < 32) wcol[tid] = Wsl[tid * 32 + g];
    __syncthreads();
    float a = 0.f;
    #pragma unroll
    for (int d = 0; d < 32; ++d) a += Wx[tid * 256 + h * 32 + d] * wcol[d];
    (wcat + 65536)[(long)hc * 256 + tid] = __float2bfloat16(a);
    if (tid == 0) {
        float s = bsl[g];
        #pragma unroll
        for (int d = 0; d < 32; ++d) s += bx[h * 32 + d] * wcol[d];
        bcomb[hc] = s;
    }
}

// ---------------------------------------------------------------------------
// Kernel 1 (MFMA, 8 waves / 512 thr): LN1 + GEMM + slice softmax + FUSED
// st-partials (r26-proven).
// ---------------------------------------------------------------------------
__global__ __launch_bounds__(512, 4) void k1_mfma(
    const float* __restrict__ fx,
    const float* __restrict__ g1, const float* __restrict__ b1,
    const __hip_bfloat16* __restrict__ wcat,   // [512][256]
    const float* __restrict__ bfx, const float* __restrict__ bcomb,
    const float* __restrict__ temp,
    float* __restrict__ psum_o, float* __restrict__ pn_o,
    __hip_bfloat16* __restrict__ sw_o)
{
    __shared__ __align__(16) char lds[65536];
    const int tid = threadIdx.x;
    const int lane = tid & 63, wid = tid >> 6;   // 8 waves
    const long tok0 = (long)blockIdx.x * 64;
    const int col = lane & 15, kq = lane >> 4;
    const int swz = (col & 7) << 4;
    const int ep = ((kq * 16) ^ swz) & 48;
    const int e0 = (swz & 64) | ep;
    const int e1 = ((swz & 64) ^ 64) | ep;
    const int ab0 = col * 512 + e0, ab1 = col * 512 + e1;

    {
        const float4 gv = *reinterpret_cast<const float4*>(g1 + lane * 4);
        const float4 bv = *reinterpret_cast<const float4*>(b1 + lane * 4);
        #pragma unroll
        for (int tt = 0; tt < 8; ++tt) {
            const int r = wid * 8 + tt;
            const float4 v = *reinterpret_cast<const float4*>(fx + (tok0 + r) * 256 + lane * 4);
            float s = v.x + v.y + v.z + v.w;
            float s2 = v.x * v.x + v.y * v.y + v.z * v.z + v.w * v.w;
            #pragma unroll
            for (int off = 32; off; off >>= 1) {
                s  += __shfl_xor(s,  off);
                s2 += __shfl_xor(s2, off);
            }
            const float mean = s * (1.f / 256.f);
            const float rs = rsqrtf(s2 * (1.f / 256.f) - mean * mean + 1e-5f);
            short4v o;
            o[0] = f2bf((v.x - mean) * rs * gv.x + bv.x);
            o[1] = f2bf((v.y - mean) * rs * gv.y + bv.y);
            o[2] = f2bf((v.z - mean) * rs * gv.z + bv.z);
            o[3] = f2bf((v.w - mean) * rs * gv.w + bv.w);
            const int addr = r * 512 + ((lane * 8) ^ ((r & 7) << 4));
            *reinterpret_cast<short4v*>(lds + addr) = o;
        }
    }
    __syncthreads();

    const int n0 = wid * 64;
    f32x4 acc[4][4];
    #pragma unroll
    for (int mt = 0; mt < 4; ++mt)
        #pragma unroll
        for (int nt = 0; nt < 4; ++nt) acc[mt][nt] = (f32x4){0.f, 0.f, 0.f, 0.f};

    const short* wp = reinterpret_cast<const short*>(wcat) + (n0 + col) * 256 + kq * 8;
    #pragma unroll 2
    for (int j = 0; j < 4; ++j) {
        short8v a0[4], a1[4];
        #pragma unroll
        for (int mt = 0; mt < 4; ++mt) {
            a0[mt] = *reinterpret_cast<const short8v*>(lds + mt * 8192 + j * 128 + ab0);
            a1[mt] = *reinterpret_cast<const short8v*>(lds + mt * 8192 + j * 128 + ab1);
        }
        #pragma unroll
        for (int nt = 0; nt < 4; ++nt) {
            const short8v b0 = *reinterpret_cast<const short8v*>(wp + nt * 4096 + j * 64);
            const short8v b1 = *reinterpret_cast<const short8v*>(wp + nt * 4096 + j * 64 + 32);
            #pragma unroll
            for (int mt = 0; mt < 4; ++mt) {
                acc[mt][nt] = __builtin_amdgcn_mfma_f32_16x16x32_bf16(a0[mt], b0, acc[mt][nt], 0, 0, 0);
                acc[mt][nt] = __builtin_amdgcn_mfma_f32_16x16x32_bf16(a1[mt], b1, acc[mt][nt], 0, 0, 0);
            }
        }
    }
    __syncthreads();

    #pragma unroll
    for (int nt = 0; nt < 4; ++nt) {
        const int c = n0 + nt * 16 + col;
        const float bb = (c < 256) ? bfx[c] : bcomb[c - 256];
        #pragma unroll
        for (int mt = 0; mt < 4; ++mt) {
            #pragma unroll
            for (int r = 0; r < 4; ++r) {
                const int row = mt * 16 + kq * 4 + r;
                const int byte = row * 1024 + ((c * 2) ^ ((row & 7) << 4));
                *reinterpret_cast<short*>(lds + byte) = f2bf(acc[mt][nt][r] + bb);
            }
        }
    }
    __syncthreads();

    // ---- slice softmax on logits (cols 256-511), in place ----
    {
        const int t = tid >> 3, h = tid & 7;
        const float it_ = 1.f / temp[h];
        float lg[32];
        #pragma unroll
        for (int g = 0; g < 32; ++g) {
            const int byte = t * 1024 + (((256 + h * 32 + g) * 2) ^ ((t & 7) << 4));
            lg[g] = bf2f(*reinterpret_cast<const short*>(lds + byte)) * it_;
        }
        float mx = -1e30f;
        #pragma unroll
        for (int g = 0; g < 32; ++g) mx = fmaxf(mx, lg[g]);
        float ssum = 0.f;
        #pragma unroll
        for (int g = 0; g < 32; ++g) { lg[g] = __expf(lg[g] - mx); ssum += lg[g]; }
        const float inv = 1.f / ssum;
        #pragma unroll
        for (int g = 0; g < 32; ++g) {
            const int byte = t * 1024 + (((256 + h * 32 + g) * 2) ^ ((t & 7) << 4));
            *reinterpret_cast<short*>(lds + byte) = f2bf(lg[g] * inv);
        }
    }
    __syncthreads();

    // ---- coalesced sw store (cols 256-511) ----
    #pragma unroll
    for (int it = 0; it < 4; ++it) {
        const int idx = it * 512 + tid;
        const int row = idx >> 5, ch = idx & 31;
        const short8v val = *reinterpret_cast<const short8v*>(
            lds + row * 1024 + ((512 + ch * 16) ^ ((row & 7) << 4)));
        *reinterpret_cast<short8v*>(
            reinterpret_cast<short*>(sw_o) + (tok0 + row) * 256 + ch * 8) = val;
    }

    // ---- FUSED st partials: wave = head, lane = (gB,dB); broadcast reads ----
    {
        const int h = wid;
        const int gB = lane >> 3, dB = lane & 7;
        const int csw = (256 + h * 32 + gB * 4) * 2;   // 8B-aligned
        const int cfx = (h * 32 + dB * 4) * 2;         // 8B-aligned
        float pac[4][4];
        float nacc[4];
        #pragma unroll
        for (int i = 0; i < 4; ++i) {
            nacc[i] = 0.f;
            #pragma unroll
            for (int j = 0; j < 4; ++j) pac[i][j] = 0.f;
        }
        #pragma unroll 4
        for (int t = 0; t < 64; ++t) {
            const int sb = t * 1024;
            const int sx = (t & 7) << 4;
            const short4v s4 = *reinterpret_cast<const short4v*>(lds + sb + (csw ^ sx));
            const short4v f4 = *reinterpret_cast<const short4v*>(lds + sb + (cfx ^ sx));
            float sg[4], fd[4];
            #pragma unroll
            for (int i = 0; i < 4; ++i) { sg[i] = bf2f(s4[i]); fd[i] = bf2f(f4[i]); }
            #pragma unroll
            for (int gg = 0; gg < 4; ++gg) {
                nacc[gg] += sg[gg];
                #pragma unroll
                for (int dd = 0; dd < 4; ++dd) pac[gg][dd] += sg[gg] * fd[dd];
            }
        }
        float* pg = psum_o + (long)blockIdx.x * 8192 + h * 1024;
        #pragma unroll
        for (int gg = 0; gg < 4; ++gg) {
            f32x4 v;
            v[0] = pac[gg][0]; v[1] = pac[gg][1];
            v[2] = pac[gg][2]; v[3] = pac[gg][3];
            *reinterpret_cast<f32x4*>(pg + (gB * 4 + gg) * 32 + dB * 4) = v;
        }
        if (dB == 0) {
            #pragma unroll
            for (int gg = 0; gg < 4; ++gg)
                pn_o[blockIdx.x * 256 + h * 32 + gB * 4 + gg] = nacc[gg];
        }
    }
}

// ---------------------------------------------------------------------------
// Kernel 2' : reduce 16 per-k1-block partials -> pst/pn (r26-proven).
// ---------------------------------------------------------------------------
__global__ __launch_bounds__(256) void k2_reduce(
    const float* __restrict__ psum_g, const float* __restrict__ pn_g,
    float* __restrict__ pst, float* __restrict__ pn)
{
    const int blk = blockIdx.x;          // [0,512): row index consumed by k3
    const int bh = blk >> 5, c = blk & 31;
    const int b = bh >> 3, h = bh & 7;
    const int i0 = b * 512 + c * 16;     // first source k1-block
    const int tid = threadIdx.x;
    const int e4 = tid * 4;              // 256 thr x 4 floats = 1024
    f32x4 s = (f32x4){0.f, 0.f, 0.f, 0.f};
    #pragma unroll 4
    for (int j = 0; j < 16; ++j) {
        const f32x4 v = *reinterpret_cast<const f32x4*>(
            psum_g + ((long)(i0 + j) * 8 + h) * 1024 + e4);
        s[0] += v[0]; s[1] += v[1]; s[2] += v[2]; s[3] += v[3];
    }
    *reinterpret_cast<f32x4*>(pst + (long)blk * 1024 + e4) = s;
    if (tid < 32) {
        float t = 0.f;
        #pragma unroll
        for (int j = 0; j < 16; ++j)
            t += pn_g[(i0 + j) * 256 + h * 32 + tid];
        pn[blk * 32 + tid] = t;
    }
}

// ---------------------------------------------------------------------------
// Kernel 3: reduce partials -> st; slice self-attn + cross-attn -> ostT (bf16).
// ---------------------------------------------------------------------------
__global__ __launch_bounds__(256) void k3_slice_attn(
    const float* __restrict__ pst, const float* __restrict__ pn,
    const float* __restrict__ ctx,
    const float* __restrict__ Wq, const float* __restrict__ Wk, const float* __restrict__ Wv,
    const float* __restrict__ Wcq, const float* __restrict__ bcq,
    const float* __restrict__ Wck, const float* __restrict__ bck,
    const float* __restrict__ Wcv, const float* __restrict__ bcv,
    const float* __restrict__ mix, __hip_bfloat16* __restrict__ ostT_o)
{
    __shared__ float st[1024], qm[1024], km[1024], vm[1024], cqm[1024];
    __shared__ float ckm[2048], cvm[2048], attn[2048], stok[1024], nb[32];
    const int tid = threadIdx.x;
    const int bh = blockIdx.x;

    if (tid < 32) {
        float s = 0.f;
        for (int c = 0; c < 32; ++c) s += pn[(bh * 32 + c) * 32 + tid];
        nb[tid] = s;
    }
    __syncthreads();
    for (int i = tid; i < 1024; i += 256) {
        float s = 0.f;
        for (int c = 0; c < 32; ++c) s += pst[(long)(bh * 32 + c) * 1024 + i];
        st[i] = s / (nb[i >> 5] + 1e-5f);
    }
    __syncthreads();

    for (int i = tid; i < 1024; i += 256) {
        const int g = i >> 5, d = i & 31;
        float aq = 0.f, ak = 0.f, av = 0.f, ac = bcq[d];
        #pragma unroll
        for (int e = 0; e < 32; ++e) {
            const float s = st[g * 32 + e];
            aq += s * Wq[e * 32 + d];
            ak += s * Wk[e * 32 + d];
            av += s * Wv[e * 32 + d];
            ac += s * Wcq[e * 32 + d];
        }
        qm[i] = aq; km[i] = ak; vm[i] = av; cqm[i] = ac;
    }
    const float* cbp = ctx + (long)bh * (NSC * NDC);
    for (int i = tid; i < 2048; i += 256) {
        const int s_ = i >> 5, d = i & 31;
        float w1 = bck[d], w2 = bcv[d];
        #pragma unroll
        for (int e = 0; e < 32; ++e) {
            const float cval = cbp[s_ * 32 + e];
            w1 += cval * Wck[e * 32 + d];
            w2 += cval * Wcv[e * 32 + d];
        }
        ckm[i] = w1; cvm[i] = w2;
    }
    __syncthreads();

    const float scale = 0.17677669529663687f;
    for (int i = tid; i < 1024; i += 256) {
        const int g = i >> 5, m = i & 31;
        float a = 0.f;
        #pragma unroll
        for (int d = 0; d < 32; ++d) a += qm[g * 32 + d] * km[m * 32 + d];
        attn[i] = a * scale;
    }
    __syncthreads();
    if (tid < 32) {
        float mx = -1e30f;
        for (int m = 0; m < 32; ++m) mx = fmaxf(mx, attn[tid * 32 + m]);
        float s = 0.f;
        for (int m = 0; m < 32; ++m) { const float e = expf(attn[tid * 32 + m] - mx); attn[tid * 32 + m] = e; s += e; }
        const float inv = 1.f / s;
        for (int m = 0; m < 32; ++m) attn[tid * 32 + m] *= inv;
    }
    __syncthreads();
    for (int i = tid; i < 1024; i += 256) {
        const int g = i >> 5, d = i & 31;
        float a = 0.f;
        #pragma unroll
        for (int m = 0; m < 32; ++m) a += attn[g * 32 + m] * vm[m * 32 + d];
        stok[i] = a;
    }
    __syncthreads();
    for (int i = tid; i < 2048; i += 256) {
        const int g = i >> 6, s_ = i & 63;
        float a = 0.f;
        #pragma unroll
        for (int d = 0; d < 32; ++d) a += cqm[g * 32 + d] * ckm[s_ * 32 + d];
        attn[i] = a * scale;
    }
    __syncthreads();
    if (tid < 32) {
        float mx = -1e30f;
        for (int m = 0; m < 64; ++m) mx = fmaxf(mx, attn[tid * 64 + m]);
        float s = 0.f;
        for (int m = 0; m < 64; ++m) { const float e = expf(attn[tid * 64 + m] - mx); attn[tid * 64 + m] = e; s += e; }
        const float inv = 1.f / s;
        for (int m = 0; m < 64; ++m) attn[tid * 64 + m] *= inv;
    }
    __syncthreads();
    const float mw = 1.f / (1.f + expf(-mix[0]));
    for (int i = tid; i < 1024; i += 256) {
        const int g = i >> 5, d = i & 31;
        float a = 0.f;
        #pragma unroll
        for (int s_ = 0; s_ < 64; ++s_) a += attn[g * 64 + s_] * cvm[s_ * 32 + d];
        const float val = mw * stok[i] + (1.f - mw) * a;
        ostT_o[(long)bh * 1024 + d * 32 + g] = __float2bfloat16(val);
    }
}

// ---------------------------------------------------------------------------
// Kernel 45 (fused, 8 waves, 64KB LDS): de-slice + Wout GEMM + LN2 + MLP.
// r27: attn-out staged bf16 in [32K,64K) (not f32 across all LDS) -> LN2
// writes the MLP A-tile directly into [0,32K): one barrier fewer, no aout
// register buffering (less spill under the 64-reg clamp).
// ---------------------------------------------------------------------------
__global__ __launch_bounds__(512, 4) void k45_fused(
    const __hip_bfloat16* __restrict__ sw, const __hip_bfloat16* __restrict__ ostT,
    const __hip_bfloat16* __restrict__ woutt, const float* __restrict__ bout,
    const float* __restrict__ fx,
    const float* __restrict__ g2, const float* __restrict__ b2,
    const __hip_bfloat16* __restrict__ w1t, const float* __restrict__ bm1,
    const __hip_bfloat16* __restrict__ w2t, const float* __restrict__ bm2,
    float* __restrict__ out)
{
    __shared__ __align__(16) char lds[65536];
    const int tid = threadIdx.x;
    const int lane = tid & 63, wid = tid >> 6;   // 8 waves
    const long tok0 = (long)blockIdx.x * 64;
    const int b = (int)(tok0 >> 15);
    const int col = lane & 15, kq = lane >> 4;
    const int swz = (col & 7) << 4;
    const int ep = ((kq * 16) ^ swz) & 48;
    const int e0 = (swz & 64) | ep;
    const int e1 = ((swz & 64) ^ 64) | ep;
    const int ab0 = col * 512 + e0, ab1 = col * 512 + e1;
    const int cb0 = col * 256 + e0, cb1 = col * 256 + e1;

    // ---- stage sw -> [0,32K) bf16 swizzled ----
    #pragma unroll
    for (int it = 0; it < 4; ++it) {
        const int idx = it * 512 + tid;
        const int row = idx >> 5, ch = idx & 31;
        const short8v val = *reinterpret_cast<const short8v*>(
            reinterpret_cast<const short*>(sw) + (tok0 + row) * 256 + ch * 8);
        *reinterpret_cast<short8v*>(lds + row * 512 + ((ch * 16) ^ ((row & 7) << 4))) = val;
    }
    __syncthreads();

    // ---- de-slice via MFMA: wave handles head h = wid ----
    {
        f32x4 accal[4][2];
        const int abh = col * 512 + (((wid * 64) | (kq * 16)) ^ swz);
        short8v a[4];
        #pragma unroll
        for (int mt = 0; mt < 4; ++mt)
            a[mt] = *reinterpret_cast<const short8v*>(lds + mt * 8192 + abh);
        #pragma unroll
        for (int nt = 0; nt < 2; ++nt) {
            const int d = nt * 16 + col;
            const short8v bfr = *reinterpret_cast<const short8v*>(
                reinterpret_cast<const short*>(ostT) + ((b * 8 + wid) * 32 + d) * 32 + kq * 8);
            #pragma unroll
            for (int mt = 0; mt < 4; ++mt) {
                accal[mt][nt] = (f32x4){0.f, 0.f, 0.f, 0.f};
                accal[mt][nt] = __builtin_amdgcn_mfma_f32_16x16x32_bf16(
                    a[mt], bfr, accal[mt][nt], 0, 0, 0);
            }
        }
        #pragma unroll
        for (int nt = 0; nt < 2; ++nt) {
            const int cc = wid * 32 + nt * 16 + col;
            #pragma unroll
            for (int mt = 0; mt < 4; ++mt) {
                #pragma unroll
                for (int r = 0; r < 4; ++r) {
                    const int row = mt * 16 + kq * 4 + r;
                    const int byte = 32768 + row * 512 + ((cc * 2) ^ ((row & 7) << 4));
                    *reinterpret_cast<short*>(lds + byte) = f2bf(accal[mt][nt][r]);
                }
            }
        }
    }
    __syncthreads();

    // ---- Wout GEMM (unroll 1, per-mt scoped A-frags) ----
    f32x4 acc[4][2];
    #pragma unroll
    for (int mt = 0; mt < 4; ++mt)
        #pragma unroll
        for (int nt = 0; nt < 2; ++nt) acc[mt][nt] = (f32x4){0.f, 0.f, 0.f, 0.f};

    {
        const short* wp = reinterpret_cast<const short*>(woutt) + (wid * 32 + col) * 256 + kq * 8;
        #pragma unroll 1
        for (int j = 0; j < 4; ++j) {
            short8v b0[2], b1[2];
            #pragma unroll
            for (int nt = 0; nt < 2; ++nt) {
                b0[nt] = *reinterpret_cast<const short8v*>(wp + nt * 4096 + j * 64);
                b1[nt] = *reinterpret_cast<const short8v*>(wp + nt * 4096 + j * 64 + 32);
            }
            #pragma unroll
            for (int mt = 0; mt < 4; ++mt) {
                const short8v x0 = *reinterpret_cast<const short8v*>(lds + 32768 + mt * 8192 + j * 128 + ab0);
                const short8v x1 = *reinterpret_cast<const short8v*>(lds + 32768 + mt * 8192 + j * 128 + ab1);
                #pragma unroll
                for (int nt = 0; nt < 2; ++nt) {
                    acc[mt][nt] = __builtin_amdgcn_mfma_f32_16x16x32_bf16(x0, b0[nt], acc[mt][nt], 0, 0, 0);
                    acc[mt][nt] = __builtin_amdgcn_mfma_f32_16x16x32_bf16(x1, b1[nt], acc[mt][nt], 0, 0, 0);
                }
            }
        }
    }

    // ---- stage attn output (acc+bout) as bf16 [64][256] swizzled -> [32K,64K) ----
    __syncthreads();
    #pragma unroll
    for (int nt = 0; nt < 2; ++nt) {
        const int c = wid * 32 + nt * 16 + col;
        const float bb = bout[c];
        #pragma unroll
        for (int mt = 0; mt < 4; ++mt) {
            #pragma unroll
            for (int r = 0; r < 4; ++r) {
                const int row = mt * 16 + kq * 4 + r;
                const int byte = 32768 + row * 512 + ((c * 2) ^ ((row & 7) << 4));
                *reinterpret_cast<short*>(lds + byte) = f2bf(acc[mt][nt][r] + bb);
            }
        }
    }
    __syncthreads();

    // ---- LN2: read attn bf16 + fx; store out_attn; write A-tile [0,32K) ----
    {
        const float4 gv = *reinterpret_cast<const float4*>(g2 + lane * 4);
        const float4 bv = *reinterpret_cast<const float4*>(b2 + lane * 4);
        #pragma unroll
        for (int tt = 0; tt < 8; ++tt) {
            const int r = wid * 8 + tt;
            const int soff = (lane * 8) ^ ((r & 7) << 4);
            const short4v a4 = *reinterpret_cast<const short4v*>(lds + 32768 + r * 512 + soff);
            const float4 f4 = *reinterpret_cast<const float4*>(fx + (tok0 + r) * 256 + lane * 4);
            float4 oa;
            oa.x = bf2f(a4[0]) + f4.x;
            oa.y = bf2f(a4[1]) + f4.y;
            oa.z = bf2f(a4[2]) + f4.z;
            oa.w = bf2f(a4[3]) + f4.w;
            *reinterpret_cast<float4*>(out + (tok0 + r) * 256 + lane * 4) = oa;
            float s = oa.x + oa.y + oa.z + oa.w;
            float s2 = oa.x * oa.x + oa.y * oa.y + oa.z * oa.z + oa.w * oa.w;
            #pragma unroll
            for (int off = 32; off; off >>= 1) {
                s  += __shfl_xor(s,  off);
                s2 += __shfl_xor(s2, off);
            }
            const float mean = s * (1.f / 256.f);
            const float rs = rsqrtf(s2 * (1.f / 256.f) - mean * mean + 1e-5f);
            short4v o;
            o[0] = f2bf((oa.x - mean) * rs * gv.x + bv.x);
            o[1] = f2bf((oa.y - mean) * rs * gv.y + bv.y);
            o[2] = f2bf((oa.z - mean) * rs * gv.z + bv.z);
            o[3] = f2bf((oa.w - mean) * rs * gv.w + bv.w);
            *reinterpret_cast<short4v*>(lds + r * 512 + soff) = o;
        }
    }
    __syncthreads();

    // ---- MLP: chunk=128, A2 double-buffered (16KB each), 1 barrier/chunk ----
    const int n0 = wid * 32;
    const int h0 = wid * 16;
    const short* w1s = reinterpret_cast<const short*>(w1t) + (h0 + col) * 256 + kq * 8;
    const short* w2s = reinterpret_cast<const short*>(w2t) + (n0 + col) * 1024 + kq * 8;

    f32x4 accO[4][2];
    #pragma unroll
    for (int mt = 0; mt < 4; ++mt)
        #pragma unroll
        for (int nt = 0; nt < 2; ++nt) accO[mt][nt] = (f32x4){0.f, 0.f, 0.f, 0.f};

    for (int ch = 0; ch < 8; ++ch) {
        const int abuf = 32768 + (ch & 1) * 16384;

        f32x4 accP[4];
        #pragma unroll
        for (int mt = 0; mt < 4; ++mt) accP[mt] = (f32x4){0.f, 0.f, 0.f, 0.f};

        #pragma unroll 1
        for (int j = 0; j < 4; ++j) {
            const short8v b0 = *reinterpret_cast<const short8v*>(w1s + ch * 32768 + j * 64);
            const short8v b1 = *reinterpret_cast<const short8v*>(w1s + ch * 32768 + j * 64 + 32);
            #pragma unroll
            for (int mt = 0; mt < 4; ++mt) {
                const short8v a0 = *reinterpret_cast<const short8v*>(lds + mt * 8192 + j * 128 + ab0);
                const short8v a1 = *reinterpret_cast<const short8v*>(lds + mt * 8192 + j * 128 + ab1);
                accP[mt] = __builtin_amdgcn_mfma_f32_16x16x32_bf16(a0, b0, accP[mt], 0, 0, 0);
                accP[mt] = __builtin_amdgcn_mfma_f32_16x16x32_bf16(a1, b1, accP[mt], 0, 0, 0);
            }
        }

        {
            const float b1v = bm1[ch * 128 + h0 + col];
            const int k2i2 = (h0 + col) * 2;
            #pragma unroll
            for (int mt = 0; mt < 4; ++mt) {
                #pragma unroll
                for (int r = 0; r < 4; ++r) {
                    float m = accP[mt][r] + b1v;
                    const float u = __builtin_fmaf(0.044715f * m, m * m, m);
                    const float e = __expf(-1.5957691216057308f * u);
                    m = m * __builtin_amdgcn_rcpf(1.f + e);
                    const int row = mt * 16 + kq * 4 + r;
                    const int byte = abuf + row * 256 + (k2i2 ^ ((row & 7) << 4));
                    *reinterpret_cast<short*>(lds + byte) = f2bf(m);
                }
            }
        }
        __syncthreads();

        #pragma unroll 1
        for (int j = 0; j < 2; ++j) {
            short8v b20[2], b21[2];
            #pragma unroll
            for (int nt = 0; nt < 2; ++nt) {
                b20[nt] = *reinterpret_cast<const short8v*>(w2s + nt * 16384 + ch * 128 + j * 64);
                b21[nt] = *reinterpret_cast<const short8v*>(w2s + nt * 16384 + ch * 128 + j * 64 + 32);
            }
            #pragma unroll
            for (int mt = 0; mt < 4; ++mt) {
                const short8v x0 = *reinterpret_cast<const short8v*>(lds + abuf + mt * 4096 + j * 128 + cb0);
                const short8v x1 = *reinterpret_cast<const short8v*>(lds + abuf + mt * 4096 + j * 128 + cb1);
                #pragma unroll
                for (int nt = 0; nt < 2; ++nt) {
                    accO[mt][nt] = __builtin_amdgcn_mfma_f32_16x16x32_bf16(x0, b20[nt], accO[mt][nt], 0, 0, 0);
                    accO[mt][nt] = __builtin_amdgcn_mfma_f32_16x16x32_bf16(x1, b21[nt], accO[mt][nt], 0, 0, 0);
                }
            }
        }
    }

    // ---- epilogue: accO+bm2 -> lf; out += mlp (RMW) ----
    __syncthreads();
    float* lf = reinterpret_cast<float*>(lds);
    #pragma unroll
    for (int nt = 0; nt < 2; ++nt) {
        const int c = n0 + nt * 16 + col;
        const float b2v = bm2[c];
        #pragma unroll
        for (int mt = 0; mt < 4; ++mt) {
            #pragma unroll
            for (int r = 0; r < 4; ++r) {
                const int row = mt * 16 + kq * 4 + r;
                lf[row * 256 + c] = accO[mt][nt][r] + b2v;
            }
        }
    }
    __syncthreads();
    #pragma unroll
    for (int tt = 0; tt < 8; ++tt) {
        const int r = wid * 8 + tt;
        const float4 m4 = *reinterpret_cast<const float4*>(lf + r * 256 + lane * 4);
        const long gidx = (tok0 + r) * 256 + lane * 4;
        const float4 oa = *reinterpret_cast<const float4*>(out + gidx);
        float4 o;
        o.x = oa.x + m4.x; o.y = oa.y + m4.y;
        o.z = oa.z + m4.z; o.w = oa.w + m4.w;
        *reinterpret_cast<float4*>(out + gidx) = o;
    }
}

// ---------------------------------------------------------------------------
extern "C" void kernel_launch(void* const* d_in, const int* in_sizes, int n_in,
                              void* d_out, int out_size, void* d_ws, size_t ws_size,
                              hipStream_t stream)
{
    const float* fx   = (const float*)d_in[0];
    const float* ctx  = (const float*)d_in[1];
    const float* g1   = (const float*)d_in[2];
    const float* b1   = (const float*)d_in[3];
    const float* Wfx  = (const float*)d_in[4];
    const float* bfx  = (const float*)d_in[5];
    const float* Wx   = (const float*)d_in[6];
    const float* bx   = (const float*)d_in[7];
    const float* Wsl  = (const float*)d_in[8];
    const float* bsl  = (const float*)d_in[9];
    const float* temp = (const float*)d_in[10];
    const float* Wq   = (const float*)d_in[11];
    const float* Wk   = (const float*)d_in[12];
    const float* Wv   = (const float*)d_in[13];
    const float* Wcq  = (const float*)d_in[14];
    const float* bcq  = (const float*)d_in[15];
    const float* Wck  = (const float*)d_in[16];
    const float* bck  = (const float*)d_in[17];
    const float* Wcv  = (const float*)d_in[18];
    const float* bcv  = (const float*)d_in[19];
    const float* mix  = (const float*)d_in[20];
    const float* Wout = (const float*)d_in[21];
    const float* bout = (const float*)d_in[22];
    const float* g2   = (const float*)d_in[23];
    const float* b2   = (const float*)d_in[24];
    const float* Wm1  = (const float*)d_in[25];
    const float* bm1  = (const float*)d_in[26];
    const float* Wm2  = (const float*)d_in[27];
    const float* bm2  = (const float*)d_in[28];
    float* out = (float*)d_out;

    char* ws = (char*)d_ws;
    float* psum_g = (float*)ws;                                         // 32MB (1024x8x32x32 f32)
    __hip_bfloat16* sw   = (__hip_bfloat16*)(ws + (size_t)33554432);    // 32MB
    float* pst = (float*)(ws + (size_t)67108864);                       // 2MB
    float* pn  = (float*)(ws + (size_t)69206016);                       // 64KB
    __hip_bfloat16* ostT  = (__hip_bfloat16*)(ws + (size_t)69271552);   // 32KB
    __hip_bfloat16* wcat  = (__hip_bfloat16*)(ws + (size_t)69304320);   // 256KB [Wfx^T; Wcomb^T]
    __hip_bfloat16* woutt = (__hip_bfloat16*)(ws + (size_t)69566464);   // 128KB
    __hip_bfloat16* w1t   = (__hip_bfloat16*)(ws + (size_t)69697536);   // 512KB
    __hip_bfloat16* w2t   = (__hip_bfloat16*)(ws + (size_t)70221824);   // 512KB
    float* bcomb          = (float*)(ws + (size_t)70746112);            // 1KB
    float* pn_g           = (float*)(ws + (size_t)70747136);            // 1MB (1024x8x32 f32)

    kprep<<<896, 256, 0, stream>>>(Wfx, wcat, Wout, woutt, Wm1, w1t, Wm2, w2t,
                                   Wx, bx, Wsl, bsl, bcomb);

    k1_mfma<<<1024, 512, 0, stream>>>(fx, g1, b1, wcat, bfx, bcomb, temp,
                                      psum_g, pn_g, sw);
    k2_reduce<<<512, 256, 0, stream>>>(psum_g, pn_g, pst, pn);
    k3_slice_attn<<<16, 256, 0, stream>>>(pst, pn, ctx, Wq, Wk, Wv,
                                          Wcq, bcq, Wck, bck, Wcv, bcv, mix, ostT);
    k45_fused<<<1024, 512, 0, stream>>>(sw, ostT, woutt, bout, fx,
                                        g2, b2, w1t, bm1, w2t, bm2, out);
}